// Round 16
// baseline (809.874 us; speedup 1.0000x reference)
//
#include <hip/hip_runtime.h>
#include <hip/hip_bf16.h>

#define TOK 8192
#define DM 384
#define QKD 48
#define EM 768
#define NBLK 8
#define NVOCAB 100
#define SEQ 2048
#define HN 1664
#define HNV 1632
#define CH 8           // k-tiles (32 keys) per split-K chunk = 256 keys
#define NUNITS 2304    // compact split-K units (4 batches x 576)

using short4v = __attribute__((ext_vector_type(4))) short;
using short8 = __attribute__((ext_vector_type(8))) short;
using f32x4  = __attribute__((ext_vector_type(4))) float;

static __device__ __forceinline__ float bf2f(short s) {
    union { unsigned u; float f; } c; c.u = ((unsigned)(unsigned short)s) << 16; return c.f;
}
static __device__ __forceinline__ short f2bf(float f) {
    union { float f; unsigned u; } c; c.f = f;
    unsigned r = (c.u + 0x7FFFu + ((c.u >> 16) & 1u)) >> 16;
    return (short)r;
}
static __device__ __forceinline__ void gload_lds16(const short* g, short* l) {
    __builtin_amdgcn_global_load_lds((const __attribute__((address_space(1))) void*)g,
                                     (__attribute__((address_space(3))) void*)l, 16, 0, 0);
}

// ---------- setup: weight conversion + embedding + LN0 (one dispatch) ----------
__global__ __launch_bounds__(256) void k_setup(const float* __restrict__ expw,
        const float* __restrict__ projw, const float* __restrict__ outw,
        short* __restrict__ ewb, short* __restrict__ pwb, short* __restrict__ owb,
        const int* __restrict__ q, const float* __restrict__ freqs,
        const float* __restrict__ lng, const float* __restrict__ lnb,
        const float* __restrict__ bg0, const float* __restrict__ bb0,
        float* __restrict__ x, short* __restrict__ xn) {
    const int n1 = NBLK * HN * DM;
    for (int i = blockIdx.x * 256 + threadIdx.x; i < n1; i += gridDim.x * 256) {
        int L = i / (HN * DM); int rem = i % (HN * DM);
        int r = rem / DM; int c = rem % DM;
        float v = (r < HNV) ? expw[((size_t)L * HNV + r) * DM + c] : 0.f;
        ewb[i] = f2bf(v);
    }
    const int n2 = NBLK * DM * EM;
    for (int i = blockIdx.x * 256 + threadIdx.x; i < n2; i += gridDim.x * 256)
        pwb[i] = f2bf(projw[i]);
    const int n3 = 128 * DM;
    for (int i = blockIdx.x * 256 + threadIdx.x; i < n3; i += gridDim.x * 256) {
        int r = i / DM, c = i % DM;
        owb[i] = f2bf(r < NVOCAB ? outw[r * DM + c] : 0.f);
    }
    // embedding + LN(ln_g,ln_b) -> x ; then LN(blk_g0,blk_b0) -> xn
    int wid = blockIdx.x * 4 + (threadIdx.x >> 6);
    int lane = threadIdx.x & 63;
    float qv = (float)q[wid];
    float v[6]; float s = 0.f, s2 = 0.f;
    #pragma unroll
    for (int i = 0; i < 6; ++i) {
        int d = lane + 64 * i;
        float val;
        if (d < 192) val = sinf(qv * freqs[d]);
        else         val = cosf(qv * freqs[d - 192]);
        v[i] = val; s += val; s2 += val * val;
    }
    #pragma unroll
    for (int m = 1; m < 64; m <<= 1) { s += __shfl_xor(s, m); s2 += __shfl_xor(s2, m); }
    float mean = s * (1.f / DM);
    float var = s2 * (1.f / DM) - mean * mean;
    float rstd = rsqrtf(var + 1e-5f);
    float* xr = x + (size_t)wid * DM;
    float s3 = 0.f, s4 = 0.f;
    #pragma unroll
    for (int i = 0; i < 6; ++i) {
        int d = lane + 64 * i;
        v[i] = (v[i] - mean) * rstd * lng[d] + lnb[d];
        xr[d] = v[i];
        s3 += v[i]; s4 += v[i] * v[i];
    }
    #pragma unroll
    for (int m = 1; m < 64; m <<= 1) { s3 += __shfl_xor(s3, m); s4 += __shfl_xor(s4, m); }
    float mean2 = s3 * (1.f / DM);
    float var2 = s4 * (1.f / DM) - mean2 * mean2;
    float rstd2 = rsqrtf(var2 + 1e-5f);
    short* xo = xn + (size_t)wid * DM;
    #pragma unroll
    for (int i = 0; i < 6; ++i) {
        int d = lane + 64 * i;
        xo[d] = f2bf((v[i] - mean2) * rstd2 * bg0[d] + bb0[d]);
    }
}

// ---------- LayerNorm fp32 -> bf16 ----------
__global__ __launch_bounds__(256) void k_ln(const float* __restrict__ x,
        const float* __restrict__ g, const float* __restrict__ b,
        short* __restrict__ xn) {
    int wid = blockIdx.x * 4 + (threadIdx.x >> 6);
    int lane = threadIdx.x & 63;
    if (wid >= TOK) return;
    const float* xr = x + (size_t)wid * DM;
    float v[6]; float s = 0.f, s2 = 0.f;
    #pragma unroll
    for (int i = 0; i < 6; ++i) {
        v[i] = xr[lane + 64 * i]; s += v[i]; s2 += v[i] * v[i];
    }
    #pragma unroll
    for (int m = 1; m < 64; m <<= 1) { s += __shfl_xor(s, m); s2 += __shfl_xor(s2, m); }
    float mean = s * (1.f / DM);
    float var = s2 * (1.f / DM) - mean * mean;
    float rstd = rsqrtf(var + 1e-5f);
    short* xo = xn + (size_t)wid * DM;
    #pragma unroll
    for (int i = 0; i < 6; ++i) {
        int d = lane + 64 * i;
        xo[d] = f2bf((v[i] - mean) * rstd * g[d] + b[d]);
    }
}

// ---------- fused h-GEMM (BK=64, XOR-swizzled) + geglu + qk extraction ----------
__global__ __launch_bounds__(256) void k_gemmh(const short* __restrict__ A,
        const short* __restrict__ Bw, short* __restrict__ cat,
        short* __restrict__ vT, short* __restrict__ qhb, short* __restrict__ khb) {
    __shared__ __align__(16) short As[128 * 64];
    __shared__ __align__(16) short Bs[128 * 64];
    int m0 = blockIdx.x * 128;
    int y = blockIdx.y;
    int t = threadIdx.x;
    int wid = t >> 6, lane = t & 63;
    int wm = (wid >> 1) * 64, wn = (wid & 1) * 64;
    int lr = lane & 15, lg = lane >> 4;
    int srow = wid * 32 + (lane >> 3);
    int sck = (lane & 7) ^ (lane >> 3);
    auto bmap = [&](int row) {
        if (y < 12) {
            int sh = row >> 4;
            return 96 + (sh & 1) * 768 + y * 64 + (sh >> 1) * 16 + (row & 15);
        }
        return (row < 96) ? row : 1632 + (row - 96);
    };
    const short* srcA[4]; const short* srcB[4]; short* dstA[4]; short* dstB[4];
    #pragma unroll
    for (int i = 0; i < 4; ++i) {
        int row = srow + i * 8;
        srcA[i] = A + (size_t)(m0 + row) * DM + sck * 8;
        srcB[i] = Bw + (size_t)bmap(row) * DM + sck * 8;
        dstA[i] = As + wid * 2048 + i * 512;
        dstB[i] = Bs + wid * 2048 + i * 512;
    }
    const f32x4 vz = {0.f, 0.f, 0.f, 0.f};
    f32x4 acc[4][4];
    #pragma unroll
    for (int i = 0; i < 4; ++i)
        #pragma unroll
        for (int j = 0; j < 4; ++j) acc[i][j] = vz;
    for (int k0 = 0; k0 < DM; k0 += 64) {
        if (k0) __syncthreads();
        #pragma unroll
        for (int i = 0; i < 4; ++i) {
            gload_lds16(srcA[i] + k0, dstA[i]);
            gload_lds16(srcB[i] + k0, dstB[i]);
        }
        __syncthreads();
        #pragma unroll
        for (int ks = 0; ks < 2; ++ks) {
            short8 af[4], bfr[4];
            #pragma unroll
            for (int i = 0; i < 4; ++i) {
                int ra = wm + i * 16 + lr;
                int rb = wn + i * 16 + lr;
                af[i]  = *(const short8*)(As + ra * 64 + (((lg + ks * 4) ^ (ra & 7)) * 8));
                bfr[i] = *(const short8*)(Bs + rb * 64 + (((lg + ks * 4) ^ (rb & 7)) * 8));
            }
            #pragma unroll
            for (int i = 0; i < 4; ++i)
                #pragma unroll
                for (int j = 0; j < 4; ++j)
                    acc[i][j] = __builtin_amdgcn_mfma_f32_16x16x32_bf16(af[i], bfr[j], acc[i][j], 0, 0, 0);
        }
    }
    if (y < 12) {
        #pragma unroll
        for (int i = 0; i < 4; ++i) {
            int tok0 = m0 + wm + i * 16 + lg * 4;
            #pragma unroll
            for (int k = 0; k < 2; ++k) {
                int e = y * 64 + (wn >> 1) + k * 16 + lr;
                short vb[4];
                #pragma unroll
                for (int r = 0; r < 4; ++r) {
                    float l = acc[i][2 * k][r], pg = acc[i][2 * k + 1][r];
                    float gel = pg * 0.5f * (1.f + erff(pg * 0.70710678118654752f));
                    vb[r] = f2bf(l * gel);
                }
                if (y < 6) {
                    #pragma unroll
                    for (int r = 0; r < 4; ++r)
                        cat[(size_t)(tok0 + r) * EM + e] = vb[r];
                } else {
                    short4v pk = {vb[0], vb[1], vb[2], vb[3]};
                    *(short4v*)(vT + (size_t)(e - DM) * TOK + tok0) = pk;
                }
            }
        }
    } else {
        #pragma unroll
        for (int i = 0; i < 4; ++i)
            #pragma unroll
            for (int j = 0; j < 4; ++j) {
                int col = wn + j * 16 + lr;
                #pragma unroll
                for (int r = 0; r < 4; ++r) {
                    int tok = m0 + wm + i * 16 + lg * 4 + r;
                    short v = f2bf(acc[i][j][r]);
                    if (col < 64) qhb[(size_t)tok * 64 + col] = (col < QKD) ? v : (short)0;
                    if (col >= QKD && col < QKD + 64)
                        khb[(size_t)tok * 64 + col - QKD] = (col < 96) ? v : (short)0;
                }
            }
    }
}

// ---------- GEMM 128x128 (vocab head) ----------
template<int MODE>
__global__ __launch_bounds__(256) void k_gemm(const short* __restrict__ A,
        const short* __restrict__ Bw, int K, int lda, int ldb,
        void* __restrict__ Cp, int ldc) {
    __shared__ __align__(16) short As[128 * 32];
    __shared__ __align__(16) short Bs[128 * 32];
    int m0 = blockIdx.x * 128, n0 = blockIdx.y * 128;
    int t = threadIdx.x;
    int wid = t >> 6, lane = t & 63;
    int wm = (wid >> 1) * 64, wn = (wid & 1) * 64;
    int lr = lane & 15, lg = lane >> 4;
    int seg0 = wid * 2, seg1 = wid * 2 + 1;
    int row0 = seg0 * 16 + (lane >> 2), row1 = seg1 * 16 + (lane >> 2);
    int cu0 = (lane & 3) ^ ((row0 + (row0 >> 2)) & 3);
    int cu1 = (lane & 3) ^ ((row1 + (row1 >> 2)) & 3);
    const short* srcA0 = A + (size_t)(m0 + row0) * lda + cu0 * 8;
    const short* srcA1 = A + (size_t)(m0 + row1) * lda + cu1 * 8;
    const short* srcB0 = Bw + (size_t)(n0 + row0) * ldb + cu0 * 8;
    const short* srcB1 = Bw + (size_t)(n0 + row1) * ldb + cu1 * 8;
    short* dA0 = As + seg0 * 512; short* dA1 = As + seg1 * 512;
    short* dB0 = Bs + seg0 * 512; short* dB1 = Bs + seg1 * 512;
    const f32x4 vz = {0.f, 0.f, 0.f, 0.f};
    f32x4 acc[4][4];
    #pragma unroll
    for (int i = 0; i < 4; ++i)
        #pragma unroll
        for (int j = 0; j < 4; ++j) acc[i][j] = vz;
    for (int k0 = 0; k0 < K; k0 += 32) {
        if (k0) __syncthreads();
        gload_lds16(srcA0 + k0, dA0);
        gload_lds16(srcA1 + k0, dA1);
        gload_lds16(srcB0 + k0, dB0);
        gload_lds16(srcB1 + k0, dB1);
        __syncthreads();
        short8 af[4], bfr[4];
        #pragma unroll
        for (int i = 0; i < 4; ++i) {
            int ra = wm + i * 16 + lr;
            int rb = wn + i * 16 + lr;
            af[i]  = *(const short8*)(As + ra * 32 + ((lg ^ ((ra + (ra >> 2)) & 3)) * 8));
            bfr[i] = *(const short8*)(Bs + rb * 32 + ((lg ^ ((rb + (rb >> 2)) & 3)) * 8));
        }
        #pragma unroll
        for (int i = 0; i < 4; ++i)
            #pragma unroll
            for (int j = 0; j < 4; ++j)
                acc[i][j] = __builtin_amdgcn_mfma_f32_16x16x32_bf16(af[i], bfr[j], acc[i][j], 0, 0, 0);
    }
    int rb = m0 + wm + (lane >> 4) * 4;
    int cb = n0 + wn + lr;
    #pragma unroll
    for (int i = 0; i < 4; ++i)
        #pragma unroll
        for (int j = 0; j < 4; ++j)
            #pragma unroll
            for (int r = 0; r < 4; ++r) {
                int row = rb + i * 16 + r;
                int col = cb + j * 16;
                float v = acc[i][j][r];
                if (MODE == 0) ((short*)Cp)[(size_t)row * ldc + col] = f2bf(v);
                else if (MODE == 1) ((float*)Cp)[(size_t)row * ldc + col] += v;
                else if (col < NVOCAB) ((float*)Cp)[(size_t)row * NVOCAB + col] = v;
            }
}

// ---------- GEMM 64x128, 2 waves: proj (K=768), accumulate into fp32 x ----------
__global__ __launch_bounds__(128) void k_gemm64(const short* __restrict__ A,
        const short* __restrict__ Bw, float* __restrict__ C) {
    __shared__ __align__(16) short As[64 * 32];
    __shared__ __align__(16) short Bs[128 * 32];
    int m0 = blockIdx.x * 64, n0 = blockIdx.y * 128;
    int t = threadIdx.x;
    int wid = t >> 6, lane = t & 63;
    int wn = wid * 64;
    int lr = lane & 15, lg = lane >> 4;
    int rsub = lane >> 2;
    int rowA0 = (wid * 2) * 16 + rsub,     rowA1 = (wid * 2 + 1) * 16 + rsub;
    int rowB0 = (wid * 4) * 16 + rsub,     rowB1 = (wid * 4 + 1) * 16 + rsub;
    int rowB2 = (wid * 4 + 2) * 16 + rsub, rowB3 = (wid * 4 + 3) * 16 + rsub;
    int q4 = lane & 3;
    int cA0 = q4 ^ ((rowA0 + (rowA0 >> 2)) & 3), cA1 = q4 ^ ((rowA1 + (rowA1 >> 2)) & 3);
    int cB0 = q4 ^ ((rowB0 + (rowB0 >> 2)) & 3), cB1 = q4 ^ ((rowB1 + (rowB1 >> 2)) & 3);
    int cB2 = q4 ^ ((rowB2 + (rowB2 >> 2)) & 3), cB3 = q4 ^ ((rowB3 + (rowB3 >> 2)) & 3);
    const short* sA0 = A + (size_t)(m0 + rowA0) * EM + cA0 * 8;
    const short* sA1 = A + (size_t)(m0 + rowA1) * EM + cA1 * 8;
    const short* sB0 = Bw + (size_t)(n0 + rowB0) * EM + cB0 * 8;
    const short* sB1 = Bw + (size_t)(n0 + rowB1) * EM + cB1 * 8;
    const short* sB2 = Bw + (size_t)(n0 + rowB2) * EM + cB2 * 8;
    const short* sB3 = Bw + (size_t)(n0 + rowB3) * EM + cB3 * 8;
    short* dA0 = As + (wid * 2) * 512;     short* dA1 = As + (wid * 2 + 1) * 512;
    short* dB0 = Bs + (wid * 4) * 512;     short* dB1 = Bs + (wid * 4 + 1) * 512;
    short* dB2 = Bs + (wid * 4 + 2) * 512; short* dB3 = Bs + (wid * 4 + 3) * 512;
    const f32x4 vz = {0.f, 0.f, 0.f, 0.f};
    f32x4 acc[4][4];
    #pragma unroll
    for (int i = 0; i < 4; ++i)
        #pragma unroll
        for (int j = 0; j < 4; ++j) acc[i][j] = vz;
    for (int k0 = 0; k0 < EM; k0 += 32) {
        if (k0) __syncthreads();
        gload_lds16(sA0 + k0, dA0);
        gload_lds16(sA1 + k0, dA1);
        gload_lds16(sB0 + k0, dB0);
        gload_lds16(sB1 + k0, dB1);
        gload_lds16(sB2 + k0, dB2);
        gload_lds16(sB3 + k0, dB3);
        __syncthreads();
        short8 af[4], bfr[4];
        #pragma unroll
        for (int i = 0; i < 4; ++i) {
            int ra = i * 16 + lr;
            int rbw = wn + i * 16 + lr;
            af[i]  = *(const short8*)(As + ra * 32 + ((lg ^ ((ra + (ra >> 2)) & 3)) * 8));
            bfr[i] = *(const short8*)(Bs + rbw * 32 + ((lg ^ ((rbw + (rbw >> 2)) & 3)) * 8));
        }
        #pragma unroll
        for (int i = 0; i < 4; ++i)
            #pragma unroll
            for (int j = 0; j < 4; ++j)
                acc[i][j] = __builtin_amdgcn_mfma_f32_16x16x32_bf16(af[i], bfr[j], acc[i][j], 0, 0, 0);
    }
    int rbase = m0 + (lane >> 4) * 4;
    int cbase = n0 + wn + lr;
    #pragma unroll
    for (int i = 0; i < 4; ++i)
        #pragma unroll
        for (int j = 0; j < 4; ++j)
            #pragma unroll
            for (int r = 0; r < 4; ++r)
                C[(size_t)(rbase + i * 16 + r) * DM + cbase + j * 16] += acc[i][j][r];
}

// ---------- split-K flash v10: 8 waves / 8 q-tiles share V+K LDS ----------
// Block = (b, gq8 of 8 consecutive q-tiles, chunk). Wave w owns q-tile 8*gq8+w.
// V (24KB) + K (4KB) staged once per iteration, consumed by all 8 waves.
// Fully-masked waves (chunk beyond their causal range) produce exp->0, li+=0.
__global__ __launch_bounds__(512) void k_flash(const short* __restrict__ qhb,
        const short* __restrict__ khb, const short* __restrict__ vT,
        short* __restrict__ Po, float* __restrict__ Pml) {
    int idx = blockIdx.x;            // 512 blocks = 4b x 16gq8 x 8c
    int xcd = idx & 7;
    int b = xcd >> 1;                // batch pinned to an XCD pair
    int unit = ((idx >> 3) << 1) | (xcd & 1);   // 0..127
    int gq8 = 15 - (unit & 15);      // big groups launch first
    int c = unit >> 4;
    int nkbm = 4 * gq8 + 4;          // max nkb over the 8 q-tiles
    int kb0 = c * CH;
    if (kb0 >= nkbm) return;         // invalid chunk (uniform across block)
    int kb1 = min(kb0 + CH, nkbm);
    __shared__ __align__(16) short Vlds[384 * 40];
    __shared__ __align__(16) short Klds[32 * 64];
    __shared__ __align__(16) short Plds[8 * 16 * 40];
    int t = threadIdx.x;
    int wid = t >> 6, lane = t & 63;
    int lr = lane & 15, lg = lane >> 4;
    int qt = gq8 * 8 + wid;
    int g = qt >> 4;                 // uniform per block (group never crosses 16)
    int tb = b * SEQ;
    int q0 = qt * 16;
    short* P = Plds + wid * (16 * 40);
    const float scale = 0.14433756729740643f; // 1/sqrt(48)
    const float CFIX = 8.f;
    const f32x4 vzero = {0.f, 0.f, 0.f, 0.f};

    short8 qf[2];
    #pragma unroll
    for (int ks = 0; ks < 2; ++ks)
        qf[ks] = *(const short8*)(qhb + (size_t)(tb + q0 + lr) * 64 + ks * 32 + lg * 8);

    f32x4 o[24];
    #pragma unroll
    for (int j = 0; j < 24; ++j) o[j] = vzero;
    float li[4];
    #pragma unroll
    for (int r = 0; r < 4; ++r) li[r] = 0.f;

    // staging geometry (512 threads): V rows t>>2 (+128,+256), chunk (t&3)*8
    int vrow = t >> 2, vc = (t & 3) * 8;
    const short* vsrc0 = vT + (size_t)vrow * TOK + tb + vc;
    // K: threads 0..255 stage 32 rows x 8 chunks
    int krow = t >> 3, kc8 = (t & 7) * 8;
    const short* ksrc0 = khb + (size_t)(tb + krow) * 64 + kc8;

    short8 rv0, rv1, rv2, rk;
    rv0 = *(const short8*)(vsrc0 + (size_t)0 * TOK * 128 + kb0 * 32);
    rv1 = *(const short8*)(vsrc0 + (size_t)128 * TOK + kb0 * 32);
    rv2 = *(const short8*)(vsrc0 + (size_t)256 * TOK + kb0 * 32);
    if (t < 256) rk = *(const short8*)(ksrc0 + (size_t)kb0 * 2048);

    for (int kb = kb0; kb < kb1; ++kb) {
        int kbase = kb * 32;
        __syncthreads();             // all waves done reading previous LDS tiles
        *(short8*)(Vlds + vrow * 40 + vc) = rv0;
        *(short8*)(Vlds + (vrow + 128) * 40 + vc) = rv1;
        *(short8*)(Vlds + (vrow + 256) * 40 + vc) = rv2;
        if (t < 256) *(short8*)(Klds + krow * 64 + kc8) = rk;
        if (kb + 1 < kb1) {
            rv0 = *(const short8*)(vsrc0 + kbase + 32);
            rv1 = *(const short8*)(vsrc0 + (size_t)128 * TOK + kbase + 32);
            rv2 = *(const short8*)(vsrc0 + (size_t)256 * TOK + kbase + 32);
            if (t < 256) rk = *(const short8*)(ksrc0 + (size_t)(kb + 1) * 2048);
        }
        __syncthreads();             // staging visible to all waves
        short8 kf0a = *(const short8*)(Klds + lr * 64 + lg * 8);
        short8 kf0b = *(const short8*)(Klds + lr * 64 + 32 + lg * 8);
        short8 kf1a = *(const short8*)(Klds + (16 + lr) * 64 + lg * 8);
        short8 kf1b = *(const short8*)(Klds + (16 + lr) * 64 + 32 + lg * 8);

        f32x4 s0 = vzero, s1 = vzero;
        s0 = __builtin_amdgcn_mfma_f32_16x16x32_bf16(qf[0], kf0a, s0, 0, 0, 0);
        s0 = __builtin_amdgcn_mfma_f32_16x16x32_bf16(qf[1], kf0b, s0, 0, 0, 0);
        s1 = __builtin_amdgcn_mfma_f32_16x16x32_bf16(qf[0], kf1a, s1, 0, 0, 0);
        s1 = __builtin_amdgcn_mfma_f32_16x16x32_bf16(qf[1], kf1b, s1, 0, 0, 0);

        bool needmask = (kbase + 31 > q0);
        #pragma unroll
        for (int r = 0; r < 4; ++r) {
            float v0 = s0[r] * scale, v1 = s1[r] * scale;
            if (needmask) {
                int qg = q0 + lg * 4 + r;
                if (kbase + lr > qg) v0 = -1e30f;
                if (kbase + 16 + lr > qg) v1 = -1e30f;
            }
            float p0 = __expf(v0 - CFIX);
            float p1 = __expf(v1 - CFIX);
            li[r] += p0 + p1;
            s0[r] = p0; s1[r] = p1;
        }
        #pragma unroll
        for (int r = 0; r < 4; ++r) {
            P[(lg * 4 + r) * 40 + lr] = f2bf(s0[r]);
            P[(lg * 4 + r) * 40 + 16 + lr] = f2bf(s1[r]);
        }
        short8 pf = *(const short8*)(P + lr * 40 + lg * 8);
        #pragma unroll
        for (int j = 0; j < 24; ++j) {
            short8 vf = *(const short8*)(Vlds + (j * 16 + lr) * 40 + lg * 8);
            o[j] = __builtin_amdgcn_mfma_f32_16x16x32_bf16(pf, vf, o[j], 0, 0, 0);
        }
    }
    #pragma unroll
    for (int r = 0; r < 4; ++r) {
        float sum = li[r];
        #pragma unroll
        for (int d2 = 1; d2 < 16; d2 <<= 1) sum += __shfl_xor(sum, d2);
        li[r] = sum;
    }
    int uid = 8 * g * (g + 1) + (qt & 15) * (g + 1) + c;
    int sidx = (uid << 2) | b;
    size_t ob = (size_t)sidx * (16 * 384);
    #pragma unroll
    for (int j = 0; j < 24; ++j)
        #pragma unroll
        for (int r = 0; r < 4; ++r)
            Po[ob + (size_t)(lg * 4 + r) * 384 + j * 16 + lr] = f2bf(o[j][r]);
    if (lr == 0) {
        #pragma unroll
        for (int r = 0; r < 4; ++r)
            Pml[sidx * 32 + 16 + lg * 4 + r] = li[r];
    }
}

// ---------- combine split-K partials (all weights = 1, fixed shift) ----------
__global__ __launch_bounds__(256) void k_comb(const short* __restrict__ Po,
        const float* __restrict__ Pml, short* __restrict__ cat) {
    int bid = blockIdx.x;             // 512 = 4 batches x 128 q-tiles
    int b = bid & 3, qt = bid >> 2;
    int g = qt >> 4;
    int nch = g + 1;
    int ubase = 8 * g * (g + 1) + (qt & 15) * (g + 1);
    int tid = threadIdx.x;
    int row = tid >> 4;
    int c0 = (tid & 15) * 24;
    float L = 0.f;
    float acc[24];
    #pragma unroll
    for (int e = 0; e < 24; ++e) acc[e] = 0.f;
    #pragma unroll
    for (int c = 0; c < 8; ++c) {
        if (c < nch) {
            int uu = ((ubase + c) << 2) | b;
            L += Pml[uu * 32 + 16 + row];
            const short8* pp = (const short8*)(Po + ((size_t)uu * 16 + row) * 384 + c0);
            #pragma unroll
            for (int v = 0; v < 3; ++v) {
                short8 tv = pp[v];
                #pragma unroll
                for (int k = 0; k < 8; ++k) acc[v * 8 + k] += bf2f(tv[k]);
            }
        }
    }
    float invL = 1.f / L;
    size_t tok = (size_t)b * SEQ + qt * 16 + row;
    short* dst = cat + tok * EM + DM + c0;
    #pragma unroll
    for (int v = 0; v < 3; ++v) {
        short8 o8;
        #pragma unroll
        for (int k = 0; k < 8; ++k) o8[k] = f2bf(acc[v * 8 + k] * invL);
        *(short8*)(dst + v * 8) = o8;
    }
}

extern "C" void kernel_launch(void* const* d_in, const int* in_sizes, int n_in,
                              void* d_out, int out_size, void* d_ws, size_t ws_size,
                              hipStream_t stream) {
    const int*   q     = (const int*)d_in[0];
    const float* freqs = (const float*)d_in[1];
    const float* expw  = (const float*)d_in[2];
    const float* projw = (const float*)d_in[3];
    const float* blkg  = (const float*)d_in[4];
    const float* blkb  = (const float*)d_in[5];
    const float* lng   = (const float*)d_in[6];
    const float* lnb   = (const float*)d_in[7];
    const float* outw  = (const float*)d_in[8];
    float* out = (float*)d_out;

    char* p = (char*)d_ws;
    auto alloc = [&](size_t bytes) {
        char* r = p; p += (bytes + 255) & ~(size_t)255; return r;
    };
    float* x   = (float*)alloc((size_t)TOK * DM * 4);
    short* xn  = (short*)alloc((size_t)TOK * DM * 2);
    short* h   = (short*)alloc((size_t)TOK * HN * 2);   // dead space (backs Po)
    short* cat = (short*)alloc((size_t)TOK * EM * 2);
    short* vT  = (short*)alloc((size_t)DM * TOK * 2);
    short* qhb = (short*)alloc((size_t)TOK * 64 * 2);
    short* khb = (short*)alloc((size_t)TOK * 64 * 2);
    short* ewb = (short*)alloc((size_t)NBLK * HN * DM * 2);
    short* pwb = (short*)alloc((size_t)NBLK * DM * EM * 2);
    short* owb = (short*)alloc((size_t)128 * DM * 2);
    (void)h;
    // split-K partials alias the (dead-during-attention) xn+h region (33.5 MB)
    short* Po  = xn;                                       // 2304*16*384*2 = 28.3 MB
    float* Pml = (float*)(Po + (size_t)NUNITS * 16 * 384); // 2304*32*4 = 294 KB

    k_setup<<<2048, 256, 0, stream>>>(expw, projw, outw, ewb, pwb, owb,
                                      q, freqs, lng, lnb, blkg, blkb, x, xn);

    for (int L = 0; L < NBLK; ++L) {
        if (L) k_ln<<<TOK / 4, 256, 0, stream>>>(x, blkg + L * DM, blkb + L * DM, xn);
        k_gemmh<<<dim3(64, 13), 256, 0, stream>>>(xn, ewb + (size_t)L * HN * DM,
                                                  cat, vT, qhb, khb);
        k_flash<<<512, 512, 0, stream>>>(qhb, khb, vT, Po, Pml);
        k_comb<<<512, 256, 0, stream>>>(Po, Pml, cat);
        k_gemm64<<<dim3(128, 3), 128, 0, stream>>>(cat, pwb + (size_t)L * DM * EM, x);
    }
    k_ln<<<TOK / 4, 256, 0, stream>>>(x, lng, lnb, xn);
    k_gemm<2><<<dim3(64, 1), 256, 0, stream>>>(xn, owb, DM, DM, DM, out, NVOCAB);
}

// Round 17
// 743.131 us; speedup vs baseline: 1.0898x; 1.0898x over previous
//
#include <hip/hip_runtime.h>
#include <hip/hip_bf16.h>

#define TOK 8192
#define DM 384
#define QKD 48
#define EM 768
#define NBLK 8
#define NVOCAB 100
#define SEQ 2048
#define HN 1664
#define HNV 1632
#define CH 8           // k-tiles (32 keys) per split-K chunk = 256 keys
#define NUNITS 2304    // compact split-K units (4 batches x 576)

using short4v = __attribute__((ext_vector_type(4))) short;
using short8 = __attribute__((ext_vector_type(8))) short;
using f32x4  = __attribute__((ext_vector_type(4))) float;

static __device__ __forceinline__ float bf2f(short s) {
    union { unsigned u; float f; } c; c.u = ((unsigned)(unsigned short)s) << 16; return c.f;
}
static __device__ __forceinline__ short f2bf(float f) {
    union { float f; unsigned u; } c; c.f = f;
    unsigned r = (c.u + 0x7FFFu + ((c.u >> 16) & 1u)) >> 16;
    return (short)r;
}
static __device__ __forceinline__ void gload_lds16(const short* g, short* l) {
    __builtin_amdgcn_global_load_lds((const __attribute__((address_space(1))) void*)g,
                                     (__attribute__((address_space(3))) void*)l, 16, 0, 0);
}

// ---------- setup: weight conversion + embedding + LN0 (one dispatch) ----------
__global__ __launch_bounds__(256) void k_setup(const float* __restrict__ expw,
        const float* __restrict__ projw, const float* __restrict__ outw,
        short* __restrict__ ewb, short* __restrict__ pwb, short* __restrict__ owb,
        const int* __restrict__ q, const float* __restrict__ freqs,
        const float* __restrict__ lng, const float* __restrict__ lnb,
        const float* __restrict__ bg0, const float* __restrict__ bb0,
        float* __restrict__ x, short* __restrict__ xn) {
    const int n1 = NBLK * HN * DM;
    for (int i = blockIdx.x * 256 + threadIdx.x; i < n1; i += gridDim.x * 256) {
        int L = i / (HN * DM); int rem = i % (HN * DM);
        int r = rem / DM; int c = rem % DM;
        float v = (r < HNV) ? expw[((size_t)L * HNV + r) * DM + c] : 0.f;
        ewb[i] = f2bf(v);
    }
    const int n2 = NBLK * DM * EM;
    for (int i = blockIdx.x * 256 + threadIdx.x; i < n2; i += gridDim.x * 256)
        pwb[i] = f2bf(projw[i]);
    const int n3 = 128 * DM;
    for (int i = blockIdx.x * 256 + threadIdx.x; i < n3; i += gridDim.x * 256) {
        int r = i / DM, c = i % DM;
        owb[i] = f2bf(r < NVOCAB ? outw[r * DM + c] : 0.f);
    }
    // embedding + LN(ln_g,ln_b) -> x ; then LN(blk_g0,blk_b0) -> xn
    int wid = blockIdx.x * 4 + (threadIdx.x >> 6);
    int lane = threadIdx.x & 63;
    float qv = (float)q[wid];
    float v[6]; float s = 0.f, s2 = 0.f;
    #pragma unroll
    for (int i = 0; i < 6; ++i) {
        int d = lane + 64 * i;
        float val;
        if (d < 192) val = sinf(qv * freqs[d]);
        else         val = cosf(qv * freqs[d - 192]);
        v[i] = val; s += val; s2 += val * val;
    }
    #pragma unroll
    for (int m = 1; m < 64; m <<= 1) { s += __shfl_xor(s, m); s2 += __shfl_xor(s2, m); }
    float mean = s * (1.f / DM);
    float var = s2 * (1.f / DM) - mean * mean;
    float rstd = rsqrtf(var + 1e-5f);
    float* xr = x + (size_t)wid * DM;
    float s3 = 0.f, s4 = 0.f;
    #pragma unroll
    for (int i = 0; i < 6; ++i) {
        int d = lane + 64 * i;
        v[i] = (v[i] - mean) * rstd * lng[d] + lnb[d];
        xr[d] = v[i];
        s3 += v[i]; s4 += v[i] * v[i];
    }
    #pragma unroll
    for (int m = 1; m < 64; m <<= 1) { s3 += __shfl_xor(s3, m); s4 += __shfl_xor(s4, m); }
    float mean2 = s3 * (1.f / DM);
    float var2 = s4 * (1.f / DM) - mean2 * mean2;
    float rstd2 = rsqrtf(var2 + 1e-5f);
    short* xo = xn + (size_t)wid * DM;
    #pragma unroll
    for (int i = 0; i < 6; ++i) {
        int d = lane + 64 * i;
        xo[d] = f2bf((v[i] - mean2) * rstd2 * bg0[d] + bb0[d]);
    }
}

// ---------- fused h-GEMM (BK=64, XOR-swizzled) + geglu + qk extraction ----------
__global__ __launch_bounds__(256) void k_gemmh(const short* __restrict__ A,
        const short* __restrict__ Bw, short* __restrict__ cat,
        short* __restrict__ vT, short* __restrict__ qhb, short* __restrict__ khb) {
    __shared__ __align__(16) short As[128 * 64];
    __shared__ __align__(16) short Bs[128 * 64];
    int m0 = blockIdx.x * 128;
    int y = blockIdx.y;
    int t = threadIdx.x;
    int wid = t >> 6, lane = t & 63;
    int wm = (wid >> 1) * 64, wn = (wid & 1) * 64;
    int lr = lane & 15, lg = lane >> 4;
    int srow = wid * 32 + (lane >> 3);
    int sck = (lane & 7) ^ (lane >> 3);
    auto bmap = [&](int row) {
        if (y < 12) {
            int sh = row >> 4;
            return 96 + (sh & 1) * 768 + y * 64 + (sh >> 1) * 16 + (row & 15);
        }
        return (row < 96) ? row : 1632 + (row - 96);
    };
    const short* srcA[4]; const short* srcB[4]; short* dstA[4]; short* dstB[4];
    #pragma unroll
    for (int i = 0; i < 4; ++i) {
        int row = srow + i * 8;
        srcA[i] = A + (size_t)(m0 + row) * DM + sck * 8;
        srcB[i] = Bw + (size_t)bmap(row) * DM + sck * 8;
        dstA[i] = As + wid * 2048 + i * 512;
        dstB[i] = Bs + wid * 2048 + i * 512;
    }
    const f32x4 vz = {0.f, 0.f, 0.f, 0.f};
    f32x4 acc[4][4];
    #pragma unroll
    for (int i = 0; i < 4; ++i)
        #pragma unroll
        for (int j = 0; j < 4; ++j) acc[i][j] = vz;
    for (int k0 = 0; k0 < DM; k0 += 64) {
        if (k0) __syncthreads();
        #pragma unroll
        for (int i = 0; i < 4; ++i) {
            gload_lds16(srcA[i] + k0, dstA[i]);
            gload_lds16(srcB[i] + k0, dstB[i]);
        }
        __syncthreads();
        #pragma unroll
        for (int ks = 0; ks < 2; ++ks) {
            short8 af[4], bfr[4];
            #pragma unroll
            for (int i = 0; i < 4; ++i) {
                int ra = wm + i * 16 + lr;
                int rb = wn + i * 16 + lr;
                af[i]  = *(const short8*)(As + ra * 64 + (((lg + ks * 4) ^ (ra & 7)) * 8));
                bfr[i] = *(const short8*)(Bs + rb * 64 + (((lg + ks * 4) ^ (rb & 7)) * 8));
            }
            #pragma unroll
            for (int i = 0; i < 4; ++i)
                #pragma unroll
                for (int j = 0; j < 4; ++j)
                    acc[i][j] = __builtin_amdgcn_mfma_f32_16x16x32_bf16(af[i], bfr[j], acc[i][j], 0, 0, 0);
        }
    }
    if (y < 12) {
        #pragma unroll
        for (int i = 0; i < 4; ++i) {
            int tok0 = m0 + wm + i * 16 + lg * 4;
            #pragma unroll
            for (int k = 0; k < 2; ++k) {
                int e = y * 64 + (wn >> 1) + k * 16 + lr;
                short vb[4];
                #pragma unroll
                for (int r = 0; r < 4; ++r) {
                    float l = acc[i][2 * k][r], pg = acc[i][2 * k + 1][r];
                    float gel = pg * 0.5f * (1.f + erff(pg * 0.70710678118654752f));
                    vb[r] = f2bf(l * gel);
                }
                if (y < 6) {
                    #pragma unroll
                    for (int r = 0; r < 4; ++r)
                        cat[(size_t)(tok0 + r) * EM + e] = vb[r];
                } else {
                    short4v pk = {vb[0], vb[1], vb[2], vb[3]};
                    *(short4v*)(vT + (size_t)(e - DM) * TOK + tok0) = pk;
                }
            }
        }
    } else {
        #pragma unroll
        for (int i = 0; i < 4; ++i)
            #pragma unroll
            for (int j = 0; j < 4; ++j) {
                int col = wn + j * 16 + lr;
                #pragma unroll
                for (int r = 0; r < 4; ++r) {
                    int tok = m0 + wm + i * 16 + lg * 4 + r;
                    short v = f2bf(acc[i][j][r]);
                    if (col < 64) qhb[(size_t)tok * 64 + col] = (col < QKD) ? v : (short)0;
                    if (col >= QKD && col < QKD + 64)
                        khb[(size_t)tok * 64 + col - QKD] = (col < 96) ? v : (short)0;
                }
            }
    }
}

// ---------- GEMM 128x128 (vocab head) ----------
template<int MODE>
__global__ __launch_bounds__(256) void k_gemm(const short* __restrict__ A,
        const short* __restrict__ Bw, int K, int lda, int ldb,
        void* __restrict__ Cp, int ldc) {
    __shared__ __align__(16) short As[128 * 32];
    __shared__ __align__(16) short Bs[128 * 32];
    int m0 = blockIdx.x * 128, n0 = blockIdx.y * 128;
    int t = threadIdx.x;
    int wid = t >> 6, lane = t & 63;
    int wm = (wid >> 1) * 64, wn = (wid & 1) * 64;
    int lr = lane & 15, lg = lane >> 4;
    int seg0 = wid * 2, seg1 = wid * 2 + 1;
    int row0 = seg0 * 16 + (lane >> 2), row1 = seg1 * 16 + (lane >> 2);
    int cu0 = (lane & 3) ^ ((row0 + (row0 >> 2)) & 3);
    int cu1 = (lane & 3) ^ ((row1 + (row1 >> 2)) & 3);
    const short* srcA0 = A + (size_t)(m0 + row0) * lda + cu0 * 8;
    const short* srcA1 = A + (size_t)(m0 + row1) * lda + cu1 * 8;
    const short* srcB0 = Bw + (size_t)(n0 + row0) * ldb + cu0 * 8;
    const short* srcB1 = Bw + (size_t)(n0 + row1) * ldb + cu1 * 8;
    short* dA0 = As + seg0 * 512; short* dA1 = As + seg1 * 512;
    short* dB0 = Bs + seg0 * 512; short* dB1 = Bs + seg1 * 512;
    const f32x4 vz = {0.f, 0.f, 0.f, 0.f};
    f32x4 acc[4][4];
    #pragma unroll
    for (int i = 0; i < 4; ++i)
        #pragma unroll
        for (int j = 0; j < 4; ++j) acc[i][j] = vz;
    for (int k0 = 0; k0 < K; k0 += 32) {
        if (k0) __syncthreads();
        gload_lds16(srcA0 + k0, dA0);
        gload_lds16(srcA1 + k0, dA1);
        gload_lds16(srcB0 + k0, dB0);
        gload_lds16(srcB1 + k0, dB1);
        __syncthreads();
        short8 af[4], bfr[4];
        #pragma unroll
        for (int i = 0; i < 4; ++i) {
            int ra = wm + i * 16 + lr;
            int rb = wn + i * 16 + lr;
            af[i]  = *(const short8*)(As + ra * 32 + ((lg ^ ((ra + (ra >> 2)) & 3)) * 8));
            bfr[i] = *(const short8*)(Bs + rb * 32 + ((lg ^ ((rb + (rb >> 2)) & 3)) * 8));
        }
        #pragma unroll
        for (int i = 0; i < 4; ++i)
            #pragma unroll
            for (int j = 0; j < 4; ++j)
                acc[i][j] = __builtin_amdgcn_mfma_f32_16x16x32_bf16(af[i], bfr[j], acc[i][j], 0, 0, 0);
    }
    int rb = m0 + wm + (lane >> 4) * 4;
    int cb = n0 + wn + lr;
    #pragma unroll
    for (int i = 0; i < 4; ++i)
        #pragma unroll
        for (int j = 0; j < 4; ++j)
            #pragma unroll
            for (int r = 0; r < 4; ++r) {
                int row = rb + i * 16 + r;
                int col = cb + j * 16;
                float v = acc[i][j][r];
                if (MODE == 0) ((short*)Cp)[(size_t)row * ldc + col] = f2bf(v);
                else if (MODE == 1) ((float*)Cp)[(size_t)row * ldc + col] += v;
                else if (col < NVOCAB) ((float*)Cp)[(size_t)row * NVOCAB + col] = v;
            }
}

// ---------- proj GEMM (BM=32, full N=384) + residual + fused LayerNorm ----------
// grid 256 blocks, 256 threads. Wave w: cols w*96..w*96+96, rows 32.
// Epilogue: y = x_old + acc; row mean/var via shfl + cross-wave LDS reduce;
// writes x (fp32 residual) and xn = LN(y)*g+b (bf16, NEXT layer's params).
__global__ __launch_bounds__(256) void k_gemmproj(const short* __restrict__ A,
        const short* __restrict__ Bw, float* __restrict__ x,
        short* __restrict__ xn, const float* __restrict__ g,
        const float* __restrict__ b) {
    __shared__ __align__(16) short As[32 * 32];
    __shared__ __align__(16) short Bs[384 * 32];
    __shared__ float redS[4][32];
    __shared__ float redQ[4][32];
    int m0 = blockIdx.x * 32;
    int t = threadIdx.x;
    int wid = t >> 6, lane = t & 63;
    int lr = lane & 15, lg = lane >> 4;
    // staging: 26 segs (0..1 A, 2..25 B); wave w stages segs w*7..w*7+6 (guarded)
    const short* src[7]; short* dst[7]; bool valid[7];
    int rin = lane >> 2, cch = lane & 3;
    #pragma unroll
    for (int qd = 0; qd < 7; ++qd) {
        int seg = wid * 7 + qd;
        valid[qd] = (seg < 26);
        int segc = valid[qd] ? seg : 25;
        if (segc < 2) {
            int row = segc * 16 + rin;
            int cu = cch ^ ((row + (row >> 2)) & 3);
            src[qd] = A + (size_t)(m0 + row) * EM + cu * 8;
            dst[qd] = As + segc * 512;
        } else {
            int row = (segc - 2) * 16 + rin;
            int cu = cch ^ ((row + (row >> 2)) & 3);
            src[qd] = Bw + (size_t)row * EM + cu * 8;
            dst[qd] = Bs + (segc - 2) * 512;
        }
    }
    const f32x4 vz = {0.f, 0.f, 0.f, 0.f};
    f32x4 acc[2][6];
    #pragma unroll
    for (int i = 0; i < 2; ++i)
        #pragma unroll
        for (int j = 0; j < 6; ++j) acc[i][j] = vz;
    for (int k0 = 0; k0 < EM; k0 += 32) {
        if (k0) __syncthreads();
        #pragma unroll
        for (int qd = 0; qd < 7; ++qd)
            if (valid[qd]) gload_lds16(src[qd] + k0, dst[qd]);
        __syncthreads();
        short8 af[2], bfr[6];
        #pragma unroll
        for (int i = 0; i < 2; ++i) {
            int ra = i * 16 + lr;
            af[i] = *(const short8*)(As + ra * 32 + ((lg ^ ((ra + (ra >> 2)) & 3)) * 8));
        }
        #pragma unroll
        for (int j = 0; j < 6; ++j) {
            int rb = wid * 96 + j * 16 + lr;
            bfr[j] = *(const short8*)(Bs + rb * 32 + ((lg ^ ((rb + (rb >> 2)) & 3)) * 8));
        }
        #pragma unroll
        for (int i = 0; i < 2; ++i)
            #pragma unroll
            for (int j = 0; j < 6; ++j)
                acc[i][j] = __builtin_amdgcn_mfma_f32_16x16x32_bf16(af[i], bfr[j], acc[i][j], 0, 0, 0);
    }
    // epilogue: residual add + per-row stats (each wave covers 96 cols of each row)
    #pragma unroll
    for (int i = 0; i < 2; ++i) {
        float rs[4], rq[4];
        #pragma unroll
        for (int r = 0; r < 4; ++r) {
            int row = m0 + i * 16 + lg * 4 + r;
            float s = 0.f, q2 = 0.f;
            #pragma unroll
            for (int j = 0; j < 6; ++j) {
                int col = wid * 96 + j * 16 + lr;
                float yv = x[(size_t)row * DM + col] + acc[i][j][r];
                acc[i][j][r] = yv;
                s += yv; q2 += yv * yv;
            }
            #pragma unroll
            for (int m = 1; m < 16; m <<= 1) { s += __shfl_xor(s, m); q2 += __shfl_xor(q2, m); }
            rs[r] = s; rq[r] = q2;
        }
        if (lr == 0) {
            #pragma unroll
            for (int r = 0; r < 4; ++r) {
                redS[wid][i * 16 + lg * 4 + r] = rs[r];
                redQ[wid][i * 16 + lg * 4 + r] = rq[r];
            }
        }
    }
    __syncthreads();
    #pragma unroll
    for (int i = 0; i < 2; ++i)
        #pragma unroll
        for (int r = 0; r < 4; ++r) {
            int lrow = i * 16 + lg * 4 + r;
            float s = redS[0][lrow] + redS[1][lrow] + redS[2][lrow] + redS[3][lrow];
            float q2 = redQ[0][lrow] + redQ[1][lrow] + redQ[2][lrow] + redQ[3][lrow];
            float mean = s * (1.f / DM);
            float var = q2 * (1.f / DM) - mean * mean;
            float rstd = rsqrtf(var + 1e-5f);
            int row = m0 + lrow;
            #pragma unroll
            for (int j = 0; j < 6; ++j) {
                int col = wid * 96 + j * 16 + lr;
                float yv = acc[i][j][r];
                x[(size_t)row * DM + col] = yv;
                xn[(size_t)row * DM + col] = f2bf((yv - mean) * rstd * g[col] + b[col]);
            }
        }
}

// ---------- split-K flash v9 (4 waves, K+V shared via LDS) ----------
__global__ __launch_bounds__(256) void k_flash(const short* __restrict__ qhb,
        const short* __restrict__ khb, const short* __restrict__ vT,
        short* __restrict__ Po, float* __restrict__ Pml) {
    int idx = blockIdx.x;            // 1024 blocks
    int xcd = idx & 7;
    int b = xcd >> 1;
    int unit = ((idx >> 3) << 1) | (xcd & 1);
    int gq = unit & 31, c = unit >> 5;
    if (c > (gq >> 2)) return;
    __shared__ __align__(16) short Vlds[384 * 40];
    __shared__ __align__(16) short Klds[32 * 64];
    __shared__ __align__(16) short Plds[4 * 16 * 40];
    int t = threadIdx.x;
    int wid = t >> 6, lane = t & 63;
    int lr = lane & 15, lg = lane >> 4;
    int qt = gq * 4 + wid;
    int g = qt >> 4;
    int tb = b * SEQ;
    int q0 = qt * 16;
    int nkbm = 2 * gq + 2;
    int kb0 = c * CH;
    int kb1 = min(kb0 + CH, nkbm);
    short* P = Plds + wid * (16 * 40);
    const float scale = 0.14433756729740643f; // 1/sqrt(48)
    const float CFIX = 8.f;
    const f32x4 vzero = {0.f, 0.f, 0.f, 0.f};

    short8 qf[2];
    #pragma unroll
    for (int ks = 0; ks < 2; ++ks)
        qf[ks] = *(const short8*)(qhb + (size_t)(tb + q0 + lr) * 64 + ks * 32 + lg * 8);

    f32x4 o[24];
    #pragma unroll
    for (int j = 0; j < 24; ++j) o[j] = vzero;
    float li[4];
    #pragma unroll
    for (int r = 0; r < 4; ++r) li[r] = 0.f;

    int vrow = t >> 2, vc = (t & 3) * 8;
    const short* vsrc0 = vT + (size_t)vrow * TOK + tb + vc;
    int krow = t >> 3, kc8 = (t & 7) * 8;
    const short* ksrc0 = khb + (size_t)(tb + krow) * 64 + kc8;

    short8 rv[6], rk;
    #pragma unroll
    for (int i = 0; i < 6; ++i)
        rv[i] = *(const short8*)(vsrc0 + (size_t)(i * 64) * TOK + kb0 * 32);
    rk = *(const short8*)(ksrc0 + (size_t)kb0 * 2048);

    for (int kb = kb0; kb < kb1; ++kb) {
        int kbase = kb * 32;
        __syncthreads();
        #pragma unroll
        for (int i = 0; i < 6; ++i)
            *(short8*)(Vlds + (vrow + i * 64) * 40 + vc) = rv[i];
        *(short8*)(Klds + krow * 64 + kc8) = rk;
        if (kb + 1 < kb1) {
            #pragma unroll
            for (int i = 0; i < 6; ++i)
                rv[i] = *(const short8*)(vsrc0 + (size_t)(i * 64) * TOK + kbase + 32);
            rk = *(const short8*)(ksrc0 + (size_t)(kb + 1) * 2048);
        }
        __syncthreads();
        short8 kf0a = *(const short8*)(Klds + lr * 64 + lg * 8);
        short8 kf0b = *(const short8*)(Klds + lr * 64 + 32 + lg * 8);
        short8 kf1a = *(const short8*)(Klds + (16 + lr) * 64 + lg * 8);
        short8 kf1b = *(const short8*)(Klds + (16 + lr) * 64 + 32 + lg * 8);

        f32x4 s0 = vzero, s1 = vzero;
        s0 = __builtin_amdgcn_mfma_f32_16x16x32_bf16(qf[0], kf0a, s0, 0, 0, 0);
        s0 = __builtin_amdgcn_mfma_f32_16x16x32_bf16(qf[1], kf0b, s0, 0, 0, 0);
        s1 = __builtin_amdgcn_mfma_f32_16x16x32_bf16(qf[0], kf1a, s1, 0, 0, 0);
        s1 = __builtin_amdgcn_mfma_f32_16x16x32_bf16(qf[1], kf1b, s1, 0, 0, 0);

        bool needmask = (kbase + 31 > q0);
        #pragma unroll
        for (int r = 0; r < 4; ++r) {
            float v0 = s0[r] * scale, v1 = s1[r] * scale;
            if (needmask) {
                int qg = q0 + lg * 4 + r;
                if (kbase + lr > qg) v0 = -1e30f;
                if (kbase + 16 + lr > qg) v1 = -1e30f;
            }
            float p0 = __expf(v0 - CFIX);
            float p1 = __expf(v1 - CFIX);
            li[r] += p0 + p1;
            s0[r] = p0; s1[r] = p1;
        }
        #pragma unroll
        for (int r = 0; r < 4; ++r) {
            P[(lg * 4 + r) * 40 + lr] = f2bf(s0[r]);
            P[(lg * 4 + r) * 40 + 16 + lr] = f2bf(s1[r]);
        }
        short8 pf = *(const short8*)(P + lr * 40 + lg * 8);
        #pragma unroll
        for (int j = 0; j < 24; ++j) {
            short8 vf = *(const short8*)(Vlds + (j * 16 + lr) * 40 + lg * 8);
            o[j] = __builtin_amdgcn_mfma_f32_16x16x32_bf16(pf, vf, o[j], 0, 0, 0);
        }
    }
    #pragma unroll
    for (int r = 0; r < 4; ++r) {
        float sum = li[r];
        #pragma unroll
        for (int d2 = 1; d2 < 16; d2 <<= 1) sum += __shfl_xor(sum, d2);
        li[r] = sum;
    }
    int uid = 8 * g * (g + 1) + (qt & 15) * (g + 1) + c;
    int sidx = (uid << 2) | b;
    size_t ob = (size_t)sidx * (16 * 384);
    #pragma unroll
    for (int j = 0; j < 24; ++j)
        #pragma unroll
        for (int r = 0; r < 4; ++r)
            Po[ob + (size_t)(lg * 4 + r) * 384 + j * 16 + lr] = f2bf(o[j][r]);
    if (lr == 0) {
        #pragma unroll
        for (int r = 0; r < 4; ++r)
            Pml[sidx * 32 + 16 + lg * 4 + r] = li[r];
    }
}

// ---------- combine split-K partials (all weights = 1, fixed shift) ----------
__global__ __launch_bounds__(256) void k_comb(const short* __restrict__ Po,
        const float* __restrict__ Pml, short* __restrict__ cat) {
    int bid = blockIdx.x;             // 512 = 4 batches x 128 q-tiles
    int b = bid & 3, qt = bid >> 2;
    int g = qt >> 4;
    int nch = g + 1;
    int ubase = 8 * g * (g + 1) + (qt & 15) * (g + 1);
    int tid = threadIdx.x;
    int row = tid >> 4;
    int c0 = (tid & 15) * 24;
    float L = 0.f;
    float acc[24];
    #pragma unroll
    for (int e = 0; e < 24; ++e) acc[e] = 0.f;
    #pragma unroll
    for (int c = 0; c < 8; ++c) {
        if (c < nch) {
            int uu = ((ubase + c) << 2) | b;
            L += Pml[uu * 32 + 16 + row];
            const short8* pp = (const short8*)(Po + ((size_t)uu * 16 + row) * 384 + c0);
            #pragma unroll
            for (int v = 0; v < 3; ++v) {
                short8 tv = pp[v];
                #pragma unroll
                for (int k = 0; k < 8; ++k) acc[v * 8 + k] += bf2f(tv[k]);
            }
        }
    }
    float invL = 1.f / L;
    size_t tok = (size_t)b * SEQ + qt * 16 + row;
    short* dst = cat + tok * EM + DM + c0;
    #pragma unroll
    for (int v = 0; v < 3; ++v) {
        short8 o8;
        #pragma unroll
        for (int k = 0; k < 8; ++k) o8[k] = f2bf(acc[v * 8 + k] * invL);
        *(short8*)(dst + v * 8) = o8;
    }
}

extern "C" void kernel_launch(void* const* d_in, const int* in_sizes, int n_in,
                              void* d_out, int out_size, void* d_ws, size_t ws_size,
                              hipStream_t stream) {
    const int*   q     = (const int*)d_in[0];
    const float* freqs = (const float*)d_in[1];
    const float* expw  = (const float*)d_in[2];
    const float* projw = (const float*)d_in[3];
    const float* blkg  = (const float*)d_in[4];
    const float* blkb  = (const float*)d_in[5];
    const float* lng   = (const float*)d_in[6];
    const float* lnb   = (const float*)d_in[7];
    const float* outw  = (const float*)d_in[8];
    float* out = (float*)d_out;

    char* p = (char*)d_ws;
    auto alloc = [&](size_t bytes) {
        char* r = p; p += (bytes + 255) & ~(size_t)255; return r;
    };
    float* x   = (float*)alloc((size_t)TOK * DM * 4);
    short* xn  = (short*)alloc((size_t)TOK * DM * 2);
    short* h   = (short*)alloc((size_t)TOK * HN * 2);   // dead space (backs Po)
    short* cat = (short*)alloc((size_t)TOK * EM * 2);
    short* vT  = (short*)alloc((size_t)DM * TOK * 2);
    short* qhb = (short*)alloc((size_t)TOK * 64 * 2);
    short* khb = (short*)alloc((size_t)TOK * 64 * 2);
    short* ewb = (short*)alloc((size_t)NBLK * HN * DM * 2);
    short* pwb = (short*)alloc((size_t)NBLK * DM * EM * 2);
    short* owb = (short*)alloc((size_t)128 * DM * 2);
    (void)h;
    // split-K partials alias the (dead-during-attention) xn+h region (33.5 MB)
    short* Po  = xn;                                       // 2304*16*384*2 = 28.3 MB
    float* Pml = (float*)(Po + (size_t)NUNITS * 16 * 384); // 2304*32*4 = 294 KB

    k_setup<<<2048, 256, 0, stream>>>(expw, projw, outw, ewb, pwb, owb,
                                      q, freqs, lng, lnb, blkg, blkb, x, xn);

    for (int L = 0; L < NBLK; ++L) {
        k_gemmh<<<dim3(64, 13), 256, 0, stream>>>(xn, ewb + (size_t)L * HN * DM,
                                                  cat, vT, qhb, khb);
        k_flash<<<1024, 256, 0, stream>>>(qhb, khb, vT, Po, Pml);
        k_comb<<<512, 256, 0, stream>>>(Po, Pml, cat);
        const float* gn = (L < NBLK - 1) ? blkg + (L + 1) * DM : lng;
        const float* bn = (L < NBLK - 1) ? blkb + (L + 1) * DM : lnb;
        k_gemmproj<<<256, 256, 0, stream>>>(cat, pwb + (size_t)L * DM * EM, x, xn, gn, bn);
    }
    k_gemm<2><<<dim3(64, 1), 256, 0, stream>>>(xn, owb, DM, DM, DM, out, NVOCAB);
}

// Round 19
// 685.280 us; speedup vs baseline: 1.1818x; 1.0844x over previous
//
#include <hip/hip_runtime.h>
#include <hip/hip_bf16.h>

#define TOK 8192
#define DM 384
#define QKD 48
#define EM 768
#define NBLK 8
#define NVOCAB 100
#define SEQ 2048
#define HN 1664
#define HNV 1632
#define CH 8           // k-tiles (32 keys) per split-K chunk = 256 keys
#define NUNITS 2304    // compact split-K units (4 batches x 576)

using short4v = __attribute__((ext_vector_type(4))) short;
using short8 = __attribute__((ext_vector_type(8))) short;
using f32x4  = __attribute__((ext_vector_type(4))) float;

static __device__ __forceinline__ float bf2f(short s) {
    union { unsigned u; float f; } c; c.u = ((unsigned)(unsigned short)s) << 16; return c.f;
}
static __device__ __forceinline__ short f2bf(float f) {
    union { float f; unsigned u; } c; c.f = f;
    unsigned r = (c.u + 0x7FFFu + ((c.u >> 16) & 1u)) >> 16;
    return (short)r;
}
static __device__ __forceinline__ void gload_lds16(const short* g, short* l) {
    __builtin_amdgcn_global_load_lds((const __attribute__((address_space(1))) void*)g,
                                     (__attribute__((address_space(3))) void*)l, 16, 0, 0);
}

// ---------- setup: weight conversion + embedding + LN0 (one dispatch) ----------
__global__ __launch_bounds__(256) void k_setup(const float* __restrict__ expw,
        const float* __restrict__ projw, const float* __restrict__ outw,
        short* __restrict__ ewb, short* __restrict__ pwb, short* __restrict__ owb,
        const int* __restrict__ q, const float* __restrict__ freqs,
        const float* __restrict__ lng, const float* __restrict__ lnb,
        const float* __restrict__ bg0, const float* __restrict__ bb0,
        float* __restrict__ x, short* __restrict__ xn) {
    const int n1 = NBLK * HN * DM;
    for (int i = blockIdx.x * 256 + threadIdx.x; i < n1; i += gridDim.x * 256) {
        int L = i / (HN * DM); int rem = i % (HN * DM);
        int r = rem / DM; int c = rem % DM;
        float v = (r < HNV) ? expw[((size_t)L * HNV + r) * DM + c] : 0.f;
        ewb[i] = f2bf(v);
    }
    const int n2 = NBLK * DM * EM;
    for (int i = blockIdx.x * 256 + threadIdx.x; i < n2; i += gridDim.x * 256)
        pwb[i] = f2bf(projw[i]);
    const int n3 = 128 * DM;
    for (int i = blockIdx.x * 256 + threadIdx.x; i < n3; i += gridDim.x * 256) {
        int r = i / DM, c = i % DM;
        owb[i] = f2bf(r < NVOCAB ? outw[r * DM + c] : 0.f);
    }
    // embedding + LN(ln_g,ln_b) -> x ; then LN(blk_g0,blk_b0) -> xn
    int wid = blockIdx.x * 4 + (threadIdx.x >> 6);
    int lane = threadIdx.x & 63;
    float qv = (float)q[wid];
    float v[6]; float s = 0.f, s2 = 0.f;
    #pragma unroll
    for (int i = 0; i < 6; ++i) {
        int d = lane + 64 * i;
        float val;
        if (d < 192) val = sinf(qv * freqs[d]);
        else         val = cosf(qv * freqs[d - 192]);
        v[i] = val; s += val; s2 += val * val;
    }
    #pragma unroll
    for (int m = 1; m < 64; m <<= 1) { s += __shfl_xor(s, m); s2 += __shfl_xor(s2, m); }
    float mean = s * (1.f / DM);
    float var = s2 * (1.f / DM) - mean * mean;
    float rstd = rsqrtf(var + 1e-5f);
    float* xr = x + (size_t)wid * DM;
    float s3 = 0.f, s4 = 0.f;
    #pragma unroll
    for (int i = 0; i < 6; ++i) {
        int d = lane + 64 * i;
        v[i] = (v[i] - mean) * rstd * lng[d] + lnb[d];
        xr[d] = v[i];
        s3 += v[i]; s4 += v[i] * v[i];
    }
    #pragma unroll
    for (int m = 1; m < 64; m <<= 1) { s3 += __shfl_xor(s3, m); s4 += __shfl_xor(s4, m); }
    float mean2 = s3 * (1.f / DM);
    float var2 = s4 * (1.f / DM) - mean2 * mean2;
    float rstd2 = rsqrtf(var2 + 1e-5f);
    short* xo = xn + (size_t)wid * DM;
    #pragma unroll
    for (int i = 0; i < 6; ++i) {
        int d = lane + 64 * i;
        xo[d] = f2bf((v[i] - mean2) * rstd2 * bg0[d] + bb0[d]);
    }
}

// ---------- fused h-GEMM (BK=64, XOR-swizzled) + geglu + qk extraction ----------
__global__ __launch_bounds__(256) void k_gemmh(const short* __restrict__ A,
        const short* __restrict__ Bw, short* __restrict__ cat,
        short* __restrict__ vT, short* __restrict__ qhb, short* __restrict__ khb) {
    __shared__ __align__(16) short As[128 * 64];
    __shared__ __align__(16) short Bs[128 * 64];
    int m0 = blockIdx.x * 128;
    int y = blockIdx.y;
    int t = threadIdx.x;
    int wid = t >> 6, lane = t & 63;
    int wm = (wid >> 1) * 64, wn = (wid & 1) * 64;
    int lr = lane & 15, lg = lane >> 4;
    int srow = wid * 32 + (lane >> 3);
    int sck = (lane & 7) ^ (lane >> 3);
    auto bmap = [&](int row) {
        if (y < 12) {
            int sh = row >> 4;
            return 96 + (sh & 1) * 768 + y * 64 + (sh >> 1) * 16 + (row & 15);
        }
        return (row < 96) ? row : 1632 + (row - 96);
    };
    const short* srcA[4]; const short* srcB[4]; short* dstA[4]; short* dstB[4];
    #pragma unroll
    for (int i = 0; i < 4; ++i) {
        int row = srow + i * 8;
        srcA[i] = A + (size_t)(m0 + row) * DM + sck * 8;
        srcB[i] = Bw + (size_t)bmap(row) * DM + sck * 8;
        dstA[i] = As + wid * 2048 + i * 512;
        dstB[i] = Bs + wid * 2048 + i * 512;
    }
    const f32x4 vz = {0.f, 0.f, 0.f, 0.f};
    f32x4 acc[4][4];
    #pragma unroll
    for (int i = 0; i < 4; ++i)
        #pragma unroll
        for (int j = 0; j < 4; ++j) acc[i][j] = vz;
    for (int k0 = 0; k0 < DM; k0 += 64) {
        if (k0) __syncthreads();
        #pragma unroll
        for (int i = 0; i < 4; ++i) {
            gload_lds16(srcA[i] + k0, dstA[i]);
            gload_lds16(srcB[i] + k0, dstB[i]);
        }
        __syncthreads();
        #pragma unroll
        for (int ks = 0; ks < 2; ++ks) {
            short8 af[4], bfr[4];
            #pragma unroll
            for (int i = 0; i < 4; ++i) {
                int ra = wm + i * 16 + lr;
                int rb = wn + i * 16 + lr;
                af[i]  = *(const short8*)(As + ra * 64 + (((lg + ks * 4) ^ (ra & 7)) * 8));
                bfr[i] = *(const short8*)(Bs + rb * 64 + (((lg + ks * 4) ^ (rb & 7)) * 8));
            }
            #pragma unroll
            for (int i = 0; i < 4; ++i)
                #pragma unroll
                for (int j = 0; j < 4; ++j)
                    acc[i][j] = __builtin_amdgcn_mfma_f32_16x16x32_bf16(af[i], bfr[j], acc[i][j], 0, 0, 0);
        }
    }
    if (y < 12) {
        #pragma unroll
        for (int i = 0; i < 4; ++i) {
            int tok0 = m0 + wm + i * 16 + lg * 4;
            #pragma unroll
            for (int k = 0; k < 2; ++k) {
                int e = y * 64 + (wn >> 1) + k * 16 + lr;
                short vb[4];
                #pragma unroll
                for (int r = 0; r < 4; ++r) {
                    float l = acc[i][2 * k][r], pg = acc[i][2 * k + 1][r];
                    float gel = pg * 0.5f * (1.f + erff(pg * 0.70710678118654752f));
                    vb[r] = f2bf(l * gel);
                }
                if (y < 6) {
                    #pragma unroll
                    for (int r = 0; r < 4; ++r)
                        cat[(size_t)(tok0 + r) * EM + e] = vb[r];
                } else {
                    short4v pk = {vb[0], vb[1], vb[2], vb[3]};
                    *(short4v*)(vT + (size_t)(e - DM) * TOK + tok0) = pk;
                }
            }
        }
    } else {
        #pragma unroll
        for (int i = 0; i < 4; ++i)
            #pragma unroll
            for (int j = 0; j < 4; ++j) {
                int col = wn + j * 16 + lr;
                #pragma unroll
                for (int r = 0; r < 4; ++r) {
                    int tok = m0 + wm + i * 16 + lg * 4 + r;
                    short v = f2bf(acc[i][j][r]);
                    if (col < 64) qhb[(size_t)tok * 64 + col] = (col < QKD) ? v : (short)0;
                    if (col >= QKD && col < QKD + 64)
                        khb[(size_t)tok * 64 + col - QKD] = (col < 96) ? v : (short)0;
                }
            }
    }
}

// ---------- GEMM 128x128 (vocab head) ----------
template<int MODE>
__global__ __launch_bounds__(256) void k_gemm(const short* __restrict__ A,
        const short* __restrict__ Bw, int K, int lda, int ldb,
        void* __restrict__ Cp, int ldc) {
    __shared__ __align__(16) short As[128 * 32];
    __shared__ __align__(16) short Bs[128 * 32];
    int m0 = blockIdx.x * 128, n0 = blockIdx.y * 128;
    int t = threadIdx.x;
    int wid = t >> 6, lane = t & 63;
    int wm = (wid >> 1) * 64, wn = (wid & 1) * 64;
    int lr = lane & 15, lg = lane >> 4;
    int seg0 = wid * 2, seg1 = wid * 2 + 1;
    int row0 = seg0 * 16 + (lane >> 2), row1 = seg1 * 16 + (lane >> 2);
    int cu0 = (lane & 3) ^ ((row0 + (row0 >> 2)) & 3);
    int cu1 = (lane & 3) ^ ((row1 + (row1 >> 2)) & 3);
    const short* srcA0 = A + (size_t)(m0 + row0) * lda + cu0 * 8;
    const short* srcA1 = A + (size_t)(m0 + row1) * lda + cu1 * 8;
    const short* srcB0 = Bw + (size_t)(n0 + row0) * ldb + cu0 * 8;
    const short* srcB1 = Bw + (size_t)(n0 + row1) * ldb + cu1 * 8;
    short* dA0 = As + seg0 * 512; short* dA1 = As + seg1 * 512;
    short* dB0 = Bs + seg0 * 512; short* dB1 = Bs + seg1 * 512;
    const f32x4 vz = {0.f, 0.f, 0.f, 0.f};
    f32x4 acc[4][4];
    #pragma unroll
    for (int i = 0; i < 4; ++i)
        #pragma unroll
        for (int j = 0; j < 4; ++j) acc[i][j] = vz;
    for (int k0 = 0; k0 < K; k0 += 32) {
        if (k0) __syncthreads();
        gload_lds16(srcA0 + k0, dA0);
        gload_lds16(srcA1 + k0, dA1);
        gload_lds16(srcB0 + k0, dB0);
        gload_lds16(srcB1 + k0, dB1);
        __syncthreads();
        short8 af[4], bfr[4];
        #pragma unroll
        for (int i = 0; i < 4; ++i) {
            int ra = wm + i * 16 + lr;
            int rb = wn + i * 16 + lr;
            af[i]  = *(const short8*)(As + ra * 32 + ((lg ^ ((ra + (ra >> 2)) & 3)) * 8));
            bfr[i] = *(const short8*)(Bs + rb * 32 + ((lg ^ ((rb + (rb >> 2)) & 3)) * 8));
        }
        #pragma unroll
        for (int i = 0; i < 4; ++i)
            #pragma unroll
            for (int j = 0; j < 4; ++j)
                acc[i][j] = __builtin_amdgcn_mfma_f32_16x16x32_bf16(af[i], bfr[j], acc[i][j], 0, 0, 0);
    }
    int rb = m0 + wm + (lane >> 4) * 4;
    int cb = n0 + wn + lr;
    #pragma unroll
    for (int i = 0; i < 4; ++i)
        #pragma unroll
        for (int j = 0; j < 4; ++j)
            #pragma unroll
            for (int r = 0; r < 4; ++r) {
                int row = rb + i * 16 + r;
                int col = cb + j * 16;
                float v = acc[i][j][r];
                if (MODE == 0) ((short*)Cp)[(size_t)row * ldc + col] = f2bf(v);
                else if (MODE == 1) ((float*)Cp)[(size_t)row * ldc + col] += v;
                else if (col < NVOCAB) ((float*)Cp)[(size_t)row * NVOCAB + col] = v;
            }
}

// ---------- proj GEMM + inline split-K combine + residual + fused LayerNorm ----------
// Block = 32 tokens (within-batch q-tiles share g => uniform chunk count).
__global__ __launch_bounds__(256) void k_gemmproj(const short* __restrict__ cat,
        const short* __restrict__ Po, const float* __restrict__ Pml,
        const short* __restrict__ Bw, float* __restrict__ x,
        short* __restrict__ xn, const float* __restrict__ g,
        const float* __restrict__ b) {
    __shared__ __align__(16) short Afull[32 * 776];
    __shared__ __align__(16) short Bs[384 * 32];
    __shared__ float redS[4][32];
    __shared__ float redQ[4][32];
    int m0 = blockIdx.x * 32;
    int t = threadIdx.x;
    int wid = t >> 6, lane = t & 63;
    int lr = lane & 15, lg = lane >> 4;
    // ---- A loc half: row t>>3, feats (t&7)*48 (6 x short8) ----
    int arow = t >> 3, ac0 = (t & 7) * 48;
    {
        const short8* src = (const short8*)(cat + (size_t)(m0 + arow) * EM + ac0);
        short* dst = Afull + arow * 776 + ac0;
        #pragma unroll
        for (int i = 0; i < 6; ++i) *(short8*)(dst + i * 8) = src[i];
    }
    // ---- A att half: combine Po chunks (weights all 1 under fixed shift) ----
    {
        int qt = (((m0 >> 4) & 127)) + (arow >> 4);   // WITHIN-BATCH q-tile (0..127)
        int bA = m0 >> 11;                            // batch
        int gg = qt >> 4;
        int nch = gg + 1;
        int rowin = arow & 15;
        int ubase = 8 * gg * (gg + 1) + (qt & 15) * (gg + 1);
        float accv[48];
        #pragma unroll
        for (int e = 0; e < 48; ++e) accv[e] = 0.f;
        float L = 0.f;
        #pragma unroll
        for (int c = 0; c < 8; ++c) {
            if (c < nch) {
                int uu = ((ubase + c) << 2) | bA;
                L += Pml[uu * 32 + 16 + rowin];
                const short8* pp = (const short8*)(Po + ((size_t)uu * 16 + rowin) * 384 + ac0);
                #pragma unroll
                for (int v = 0; v < 6; ++v) {
                    short8 tv = pp[v];
                    #pragma unroll
                    for (int k = 0; k < 8; ++k) accv[v * 8 + k] += bf2f(tv[k]);
                }
            }
        }
        float invL = 1.f / L;
        short* dst = Afull + arow * 776 + DM + ac0;
        #pragma unroll
        for (int v = 0; v < 6; ++v) {
            short8 o8;
            #pragma unroll
            for (int k = 0; k < 8; ++k) o8[k] = f2bf(accv[v * 8 + k] * invL);
            *(short8*)(dst + v * 8) = o8;
        }
    }
    // ---- B staging geometry: wave stages segs wid*6 .. wid*6+5 ----
    const short* srcB[6]; short* dstB[6];
    int rin = lane >> 2, cch = lane & 3;
    #pragma unroll
    for (int qd = 0; qd < 6; ++qd) {
        int seg = wid * 6 + qd;
        int row = seg * 16 + rin;
        int cu = cch ^ ((row + (row >> 2)) & 3);
        srcB[qd] = Bw + (size_t)row * EM + cu * 8;
        dstB[qd] = Bs + seg * 512;
    }
    const f32x4 vz = {0.f, 0.f, 0.f, 0.f};
    f32x4 acc[2][6];
    #pragma unroll
    for (int i = 0; i < 2; ++i)
        #pragma unroll
        for (int j = 0; j < 6; ++j) acc[i][j] = vz;
    for (int k0 = 0; k0 < EM; k0 += 32) {
        __syncthreads();
        #pragma unroll
        for (int qd = 0; qd < 6; ++qd)
            gload_lds16(srcB[qd] + k0, dstB[qd]);
        __syncthreads();
        short8 af[2], bfr[6];
        #pragma unroll
        for (int i = 0; i < 2; ++i)
            af[i] = *(const short8*)(Afull + (i * 16 + lr) * 776 + k0 + lg * 8);
        #pragma unroll
        for (int j = 0; j < 6; ++j) {
            int rb = wid * 96 + j * 16 + lr;
            bfr[j] = *(const short8*)(Bs + rb * 32 + ((lg ^ ((rb + (rb >> 2)) & 3)) * 8));
        }
        #pragma unroll
        for (int i = 0; i < 2; ++i)
            #pragma unroll
            for (int j = 0; j < 6; ++j)
                acc[i][j] = __builtin_amdgcn_mfma_f32_16x16x32_bf16(af[i], bfr[j], acc[i][j], 0, 0, 0);
    }
    // epilogue: residual add + per-row stats
    #pragma unroll
    for (int i = 0; i < 2; ++i) {
        float rs[4], rq[4];
        #pragma unroll
        for (int r = 0; r < 4; ++r) {
            int row = m0 + i * 16 + lg * 4 + r;
            float s = 0.f, q2 = 0.f;
            #pragma unroll
            for (int j = 0; j < 6; ++j) {
                int col = wid * 96 + j * 16 + lr;
                float yv = x[(size_t)row * DM + col] + acc[i][j][r];
                acc[i][j][r] = yv;
                s += yv; q2 += yv * yv;
            }
            #pragma unroll
            for (int m = 1; m < 16; m <<= 1) { s += __shfl_xor(s, m); q2 += __shfl_xor(q2, m); }
            rs[r] = s; rq[r] = q2;
        }
        if (lr == 0) {
            #pragma unroll
            for (int r = 0; r < 4; ++r) {
                redS[wid][i * 16 + lg * 4 + r] = rs[r];
                redQ[wid][i * 16 + lg * 4 + r] = rq[r];
            }
        }
    }
    __syncthreads();
    #pragma unroll
    for (int i = 0; i < 2; ++i)
        #pragma unroll
        for (int r = 0; r < 4; ++r) {
            int lrow = i * 16 + lg * 4 + r;
            float s = redS[0][lrow] + redS[1][lrow] + redS[2][lrow] + redS[3][lrow];
            float q2 = redQ[0][lrow] + redQ[1][lrow] + redQ[2][lrow] + redQ[3][lrow];
            float mean = s * (1.f / DM);
            float var = q2 * (1.f / DM) - mean * mean;
            float rstd = rsqrtf(var + 1e-5f);
            int row = m0 + lrow;
            #pragma unroll
            for (int j = 0; j < 6; ++j) {
                int col = wid * 96 + j * 16 + lr;
                float yv = acc[i][j][r];
                x[(size_t)row * DM + col] = yv;
                xn[(size_t)row * DM + col] = f2bf((yv - mean) * rstd * g[col] + b[col]);
            }
        }
}

// ---------- split-K flash v9 (4 waves, K+V shared via LDS) ----------
__global__ __launch_bounds__(256) void k_flash(const short* __restrict__ qhb,
        const short* __restrict__ khb, const short* __restrict__ vT,
        short* __restrict__ Po, float* __restrict__ Pml) {
    int idx = blockIdx.x;            // 1024 blocks
    int xcd = idx & 7;
    int b = xcd >> 1;
    int unit = ((idx >> 3) << 1) | (xcd & 1);
    int gq = unit & 31, c = unit >> 5;
    if (c > (gq >> 2)) return;
    __shared__ __align__(16) short Vlds[384 * 40];
    __shared__ __align__(16) short Klds[32 * 64];
    __shared__ __align__(16) short Plds[4 * 16 * 40];
    int t = threadIdx.x;
    int wid = t >> 6, lane = t & 63;
    int lr = lane & 15, lg = lane >> 4;
    int qt = gq * 4 + wid;
    int g = qt >> 4;
    int tb = b * SEQ;
    int q0 = qt * 16;
    int nkbm = 2 * gq + 2;
    int kb0 = c * CH;
    int kb1 = min(kb0 + CH, nkbm);
    short* P = Plds + wid * (16 * 40);
    const float scale = 0.14433756729740643f; // 1/sqrt(48)
    const float CFIX = 8.f;
    const f32x4 vzero = {0.f, 0.f, 0.f, 0.f};

    short8 qf[2];
    #pragma unroll
    for (int ks = 0; ks < 2; ++ks)
        qf[ks] = *(const short8*)(qhb + (size_t)(tb + q0 + lr) * 64 + ks * 32 + lg * 8);

    f32x4 o[24];
    #pragma unroll
    for (int j = 0; j < 24; ++j) o[j] = vzero;
    float li[4];
    #pragma unroll
    for (int r = 0; r < 4; ++r) li[r] = 0.f;

    int vrow = t >> 2, vc = (t & 3) * 8;
    const short* vsrc0 = vT + (size_t)vrow * TOK + tb + vc;
    int krow = t >> 3, kc8 = (t & 7) * 8;
    const short* ksrc0 = khb + (size_t)(tb + krow) * 64 + kc8;

    short8 rv[6], rk;
    #pragma unroll
    for (int i = 0; i < 6; ++i)
        rv[i] = *(const short8*)(vsrc0 + (size_t)(i * 64) * TOK + kb0 * 32);
    rk = *(const short8*)(ksrc0 + (size_t)kb0 * 2048);

    for (int kb = kb0; kb < kb1; ++kb) {
        int kbase = kb * 32;
        __syncthreads();
        #pragma unroll
        for (int i = 0; i < 6; ++i)
            *(short8*)(Vlds + (vrow + i * 64) * 40 + vc) = rv[i];
        *(short8*)(Klds + krow * 64 + kc8) = rk;
        if (kb + 1 < kb1) {
            #pragma unroll
            for (int i = 0; i < 6; ++i)
                rv[i] = *(const short8*)(vsrc0 + (size_t)(i * 64) * TOK + kbase + 32);
            rk = *(const short8*)(ksrc0 + (size_t)(kb + 1) * 2048);
        }
        __syncthreads();
        short8 kf0a = *(const short8*)(Klds + lr * 64 + lg * 8);
        short8 kf0b = *(const short8*)(Klds + lr * 64 + 32 + lg * 8);
        short8 kf1a = *(const short8*)(Klds + (16 + lr) * 64 + lg * 8);
        short8 kf1b = *(const short8*)(Klds + (16 + lr) * 64 + 32 + lg * 8);

        f32x4 s0 = vzero, s1 = vzero;
        s0 = __builtin_amdgcn_mfma_f32_16x16x32_bf16(qf[0], kf0a, s0, 0, 0, 0);
        s0 = __builtin_amdgcn_mfma_f32_16x16x32_bf16(qf[1], kf0b, s0, 0, 0, 0);
        s1 = __builtin_amdgcn_mfma_f32_16x16x32_bf16(qf[0], kf1a, s1, 0, 0, 0);
        s1 = __builtin_amdgcn_mfma_f32_16x16x32_bf16(qf[1], kf1b, s1, 0, 0, 0);

        bool needmask = (kbase + 31 > q0);
        #pragma unroll
        for (int r = 0; r < 4; ++r) {
            float v0 = s0[r] * scale, v1 = s1[r] * scale;
            if (needmask) {
                int qg = q0 + lg * 4 + r;
                if (kbase + lr > qg) v0 = -1e30f;
                if (kbase + 16 + lr > qg) v1 = -1e30f;
            }
            float p0 = __expf(v0 - CFIX);
            float p1 = __expf(v1 - CFIX);
            li[r] += p0 + p1;
            s0[r] = p0; s1[r] = p1;
        }
        #pragma unroll
        for (int r = 0; r < 4; ++r) {
            P[(lg * 4 + r) * 40 + lr] = f2bf(s0[r]);
            P[(lg * 4 + r) * 40 + 16 + lr] = f2bf(s1[r]);
        }
        short8 pf = *(const short8*)(P + lr * 40 + lg * 8);
        #pragma unroll
        for (int j = 0; j < 24; ++j) {
            short8 vf = *(const short8*)(Vlds + (j * 16 + lr) * 40 + lg * 8);
            o[j] = __builtin_amdgcn_mfma_f32_16x16x32_bf16(pf, vf, o[j], 0, 0, 0);
        }
    }
    #pragma unroll
    for (int r = 0; r < 4; ++r) {
        float sum = li[r];
        #pragma unroll
        for (int d2 = 1; d2 < 16; d2 <<= 1) sum += __shfl_xor(sum, d2);
        li[r] = sum;
    }
    int uid = 8 * g * (g + 1) + (qt & 15) * (g + 1) + c;
    int sidx = (uid << 2) | b;
    size_t ob = (size_t)sidx * (16 * 384);
    #pragma unroll
    for (int j = 0; j < 24; ++j)
        #pragma unroll
        for (int r = 0; r < 4; ++r)
            Po[ob + (size_t)(lg * 4 + r) * 384 + j * 16 + lr] = f2bf(o[j][r]);
    if (lr == 0) {
        #pragma unroll
        for (int r = 0; r < 4; ++r)
            Pml[sidx * 32 + 16 + lg * 4 + r] = li[r];
    }
}

extern "C" void kernel_launch(void* const* d_in, const int* in_sizes, int n_in,
                              void* d_out, int out_size, void* d_ws, size_t ws_size,
                              hipStream_t stream) {
    const int*   q     = (const int*)d_in[0];
    const float* freqs = (const float*)d_in[1];
    const float* expw  = (const float*)d_in[2];
    const float* projw = (const float*)d_in[3];
    const float* blkg  = (const float*)d_in[4];
    const float* blkb  = (const float*)d_in[5];
    const float* lng   = (const float*)d_in[6];
    const float* lnb   = (const float*)d_in[7];
    const float* outw  = (const float*)d_in[8];
    float* out = (float*)d_out;

    char* p = (char*)d_ws;
    auto alloc = [&](size_t bytes) {
        char* r = p; p += (bytes + 255) & ~(size_t)255; return r;
    };
    float* x   = (float*)alloc((size_t)TOK * DM * 4);
    short* xn  = (short*)alloc((size_t)TOK * DM * 2);
    short* cat = (short*)alloc((size_t)TOK * EM * 2);
    short* vT  = (short*)alloc((size_t)DM * TOK * 2);
    short* qhb = (short*)alloc((size_t)TOK * 64 * 2);
    short* khb = (short*)alloc((size_t)TOK * 64 * 2);
    short* ewb = (short*)alloc((size_t)NBLK * HN * DM * 2);
    short* pwb = (short*)alloc((size_t)NBLK * DM * EM * 2);
    short* owb = (short*)alloc((size_t)128 * DM * 2);
    short* Po  = (short*)alloc((size_t)NUNITS * 16 * 384 * 2); // 28.3 MB
    float* Pml = (float*)alloc((size_t)NUNITS * 32 * 4);       // 294 KB

    k_setup<<<2048, 256, 0, stream>>>(expw, projw, outw, ewb, pwb, owb,
                                      q, freqs, lng, lnb, blkg, blkb, x, xn);

    for (int L = 0; L < NBLK; ++L) {
        k_gemmh<<<dim3(64, 13), 256, 0, stream>>>(xn, ewb + (size_t)L * HN * DM,
                                                  cat, vT, qhb, khb);
        k_flash<<<1024, 256, 0, stream>>>(qhb, khb, vT, Po, Pml);
        const float* gn = (L < NBLK - 1) ? blkg + (L + 1) * DM : lng;
        const float* bn = (L < NBLK - 1) ? blkb + (L + 1) * DM : lnb;
        k_gemmproj<<<256, 256, 0, stream>>>(cat, Po, Pml, pwb + (size_t)L * DM * EM,
                                            x, xn, gn, bn);
    }
    k_gemm<2><<<dim3(64, 1), 256, 0, stream>>>(xn, owb, DM, DM, DM, out, NVOCAB);
}

// Round 20
// 684.868 us; speedup vs baseline: 1.1825x; 1.0006x over previous
//
#include <hip/hip_runtime.h>
#include <hip/hip_bf16.h>

#define TOK 8192
#define DM 384
#define QKD 48
#define EM 768
#define NBLK 8
#define NVOCAB 100
#define SEQ 2048
#define HN 1664
#define HNV 1632
#define CH 8           // k-tiles (32 keys) per split-K chunk = 256 keys
#define NUNITS 2304    // compact split-K units (4 batches x 576)

using short4v = __attribute__((ext_vector_type(4))) short;
using short8 = __attribute__((ext_vector_type(8))) short;
using f32x4  = __attribute__((ext_vector_type(4))) float;

static __device__ __forceinline__ float bf2f(short s) {
    union { unsigned u; float f; } c; c.u = ((unsigned)(unsigned short)s) << 16; return c.f;
}
static __device__ __forceinline__ short f2bf(float f) {
    union { float f; unsigned u; } c; c.f = f;
    unsigned r = (c.u + 0x7FFFu + ((c.u >> 16) & 1u)) >> 16;
    return (short)r;
}
static __device__ __forceinline__ void gload_lds16(const short* g, short* l) {
    __builtin_amdgcn_global_load_lds((const __attribute__((address_space(1))) void*)g,
                                     (__attribute__((address_space(3))) void*)l, 16, 0, 0);
}

// ---------- setup: weight conversion + embedding + LN0 (one dispatch) ----------
__global__ __launch_bounds__(256) void k_setup(const float* __restrict__ expw,
        const float* __restrict__ projw, const float* __restrict__ outw,
        short* __restrict__ ewb, short* __restrict__ pwb, short* __restrict__ owb,
        const int* __restrict__ q, const float* __restrict__ freqs,
        const float* __restrict__ lng, const float* __restrict__ lnb,
        const float* __restrict__ bg0, const float* __restrict__ bb0,
        float* __restrict__ x, short* __restrict__ xn) {
    const int n1 = NBLK * HN * DM;
    for (int i = blockIdx.x * 256 + threadIdx.x; i < n1; i += gridDim.x * 256) {
        int L = i / (HN * DM); int rem = i % (HN * DM);
        int r = rem / DM; int c = rem % DM;
        float v = (r < HNV) ? expw[((size_t)L * HNV + r) * DM + c] : 0.f;
        ewb[i] = f2bf(v);
    }
    const int n2 = NBLK * DM * EM;
    for (int i = blockIdx.x * 256 + threadIdx.x; i < n2; i += gridDim.x * 256)
        pwb[i] = f2bf(projw[i]);
    const int n3 = 128 * DM;
    for (int i = blockIdx.x * 256 + threadIdx.x; i < n3; i += gridDim.x * 256) {
        int r = i / DM, c = i % DM;
        owb[i] = f2bf(r < NVOCAB ? outw[r * DM + c] : 0.f);
    }
    // embedding + LN(ln_g,ln_b) -> x ; then LN(blk_g0,blk_b0) -> xn
    int wid = blockIdx.x * 4 + (threadIdx.x >> 6);
    int lane = threadIdx.x & 63;
    float qv = (float)q[wid];
    float v[6]; float s = 0.f, s2 = 0.f;
    #pragma unroll
    for (int i = 0; i < 6; ++i) {
        int d = lane + 64 * i;
        float val;
        if (d < 192) val = sinf(qv * freqs[d]);
        else         val = cosf(qv * freqs[d - 192]);
        v[i] = val; s += val; s2 += val * val;
    }
    #pragma unroll
    for (int m = 1; m < 64; m <<= 1) { s += __shfl_xor(s, m); s2 += __shfl_xor(s2, m); }
    float mean = s * (1.f / DM);
    float var = s2 * (1.f / DM) - mean * mean;
    float rstd = rsqrtf(var + 1e-5f);
    float* xr = x + (size_t)wid * DM;
    float s3 = 0.f, s4 = 0.f;
    #pragma unroll
    for (int i = 0; i < 6; ++i) {
        int d = lane + 64 * i;
        v[i] = (v[i] - mean) * rstd * lng[d] + lnb[d];
        xr[d] = v[i];
        s3 += v[i]; s4 += v[i] * v[i];
    }
    #pragma unroll
    for (int m = 1; m < 64; m <<= 1) { s3 += __shfl_xor(s3, m); s4 += __shfl_xor(s4, m); }
    float mean2 = s3 * (1.f / DM);
    float var2 = s4 * (1.f / DM) - mean2 * mean2;
    float rstd2 = rsqrtf(var2 + 1e-5f);
    short* xo = xn + (size_t)wid * DM;
    #pragma unroll
    for (int i = 0; i < 6; ++i) {
        int d = lane + 64 * i;
        xo[d] = f2bf((v[i] - mean2) * rstd2 * bg0[d] + bb0[d]);
    }
}

// ---------- fused h-GEMM, y-paired (BK=64, XOR-swizzled) + geglu + qk ----------
// Block yy<6 computes y0=2yy,y1=2yy+1 sharing one A-tile (64 MFMA/wave/barrier).
// yy==6 -> y=12 (qk extraction) alone. bmap(y1)=bmap(y0)+64 (only y*64 differs).
__global__ __launch_bounds__(256) void k_gemmh(const short* __restrict__ A,
        const short* __restrict__ Bw, short* __restrict__ cat,
        short* __restrict__ vT, short* __restrict__ qhb, short* __restrict__ khb) {
    __shared__ __align__(16) short As[128 * 64];
    __shared__ __align__(16) short Bs0[128 * 64];
    __shared__ __align__(16) short Bs1[128 * 64];
    int m0 = blockIdx.x * 128;
    int yy = blockIdx.y;                 // 0..6
    bool single = (yy == 6);
    int y0 = single ? 12 : 2 * yy;
    int t = threadIdx.x;
    int wid = t >> 6, lane = t & 63;
    int wm = (wid >> 1) * 64, wn = (wid & 1) * 64;
    int lr = lane & 15, lg = lane >> 4;
    int srow = wid * 32 + (lane >> 3);
    int sck = (lane & 7) ^ (lane >> 3);
    auto bmap = [&](int y, int row) {
        if (y < 12) {
            int sh = row >> 4;
            return 96 + (sh & 1) * 768 + y * 64 + (sh >> 1) * 16 + (row & 15);
        }
        return (row < 96) ? row : 1632 + (row - 96);
    };
    const short* srcA[4]; const short* srcB[4]; short* dstA[4]; short* dstB[4];
    #pragma unroll
    for (int i = 0; i < 4; ++i) {
        int row = srow + i * 8;
        srcA[i] = A + (size_t)(m0 + row) * DM + sck * 8;
        srcB[i] = Bw + (size_t)bmap(y0, row) * DM + sck * 8;
        dstA[i] = As + wid * 2048 + i * 512;
        dstB[i] = Bs0 + wid * 2048 + i * 512;
    }
    const f32x4 vz = {0.f, 0.f, 0.f, 0.f};
    f32x4 acc0[4][4], acc1[4][4];
    #pragma unroll
    for (int i = 0; i < 4; ++i)
        #pragma unroll
        for (int j = 0; j < 4; ++j) { acc0[i][j] = vz; acc1[i][j] = vz; }
    for (int k0 = 0; k0 < DM; k0 += 64) {
        if (k0) __syncthreads();
        #pragma unroll
        for (int i = 0; i < 4; ++i) {
            gload_lds16(srcA[i] + k0, dstA[i]);
            gload_lds16(srcB[i] + k0, dstB[i]);
        }
        if (!single) {
            // B1 rows = B0 rows + 64 elements (bmap differs only by y*64)
            #pragma unroll
            for (int i = 0; i < 4; ++i)
                gload_lds16(srcB[i] + k0 + 64 * DM / DM * 64, dstB[i] + 8192);
        }
        __syncthreads();
        #pragma unroll
        for (int ks = 0; ks < 2; ++ks) {
            short8 af[4], bfr[4];
            #pragma unroll
            for (int i = 0; i < 4; ++i) {
                int ra = wm + i * 16 + lr;
                af[i] = *(const short8*)(As + ra * 64 + (((lg + ks * 4) ^ (ra & 7)) * 8));
            }
            #pragma unroll
            for (int i = 0; i < 4; ++i) {
                int rb = wn + i * 16 + lr;
                bfr[i] = *(const short8*)(Bs0 + rb * 64 + (((lg + ks * 4) ^ (rb & 7)) * 8));
            }
            #pragma unroll
            for (int i = 0; i < 4; ++i)
                #pragma unroll
                for (int j = 0; j < 4; ++j)
                    acc0[i][j] = __builtin_amdgcn_mfma_f32_16x16x32_bf16(af[i], bfr[j], acc0[i][j], 0, 0, 0);
            if (!single) {
                #pragma unroll
                for (int i = 0; i < 4; ++i) {
                    int rb = wn + i * 16 + lr;
                    bfr[i] = *(const short8*)(Bs1 + rb * 64 + (((lg + ks * 4) ^ (rb & 7)) * 8));
                }
                #pragma unroll
                for (int i = 0; i < 4; ++i)
                    #pragma unroll
                    for (int j = 0; j < 4; ++j)
                        acc1[i][j] = __builtin_amdgcn_mfma_f32_16x16x32_bf16(af[i], bfr[j], acc1[i][j], 0, 0, 0);
            }
        }
    }
    // epilogues
    if (single) {
        // y == 12: qk extraction
        #pragma unroll
        for (int i = 0; i < 4; ++i)
            #pragma unroll
            for (int j = 0; j < 4; ++j) {
                int col = wn + j * 16 + lr;
                #pragma unroll
                for (int r = 0; r < 4; ++r) {
                    int tok = m0 + wm + i * 16 + lg * 4 + r;
                    short v = f2bf(acc0[i][j][r]);
                    if (col < 64) qhb[(size_t)tok * 64 + col] = (col < QKD) ? v : (short)0;
                    if (col >= QKD && col < QKD + 64)
                        khb[(size_t)tok * 64 + col - QKD] = (col < 96) ? v : (short)0;
                }
            }
        return;
    }
    #pragma unroll
    for (int half = 0; half < 2; ++half) {
        int y = 2 * yy + half;
        #pragma unroll
        for (int i = 0; i < 4; ++i) {
            int tok0 = m0 + wm + i * 16 + lg * 4;
            #pragma unroll
            for (int k = 0; k < 2; ++k) {
                int e = y * 64 + (wn >> 1) + k * 16 + lr;
                short vb[4];
                #pragma unroll
                for (int r = 0; r < 4; ++r) {
                    float l  = half ? acc1[i][2 * k][r]     : acc0[i][2 * k][r];
                    float pg = half ? acc1[i][2 * k + 1][r] : acc0[i][2 * k + 1][r];
                    float gel = pg * 0.5f * (1.f + erff(pg * 0.70710678118654752f));
                    vb[r] = f2bf(l * gel);
                }
                if (y < 6) {
                    #pragma unroll
                    for (int r = 0; r < 4; ++r)
                        cat[(size_t)(tok0 + r) * EM + e] = vb[r];
                } else {
                    short4v pk = {vb[0], vb[1], vb[2], vb[3]};
                    *(short4v*)(vT + (size_t)(e - DM) * TOK + tok0) = pk;
                }
            }
        }
    }
}

// ---------- GEMM 128x128 (vocab head) ----------
template<int MODE>
__global__ __launch_bounds__(256) void k_gemm(const short* __restrict__ A,
        const short* __restrict__ Bw, int K, int lda, int ldb,
        void* __restrict__ Cp, int ldc) {
    __shared__ __align__(16) short As[128 * 32];
    __shared__ __align__(16) short Bs[128 * 32];
    int m0 = blockIdx.x * 128, n0 = blockIdx.y * 128;
    int t = threadIdx.x;
    int wid = t >> 6, lane = t & 63;
    int wm = (wid >> 1) * 64, wn = (wid & 1) * 64;
    int lr = lane & 15, lg = lane >> 4;
    int seg0 = wid * 2, seg1 = wid * 2 + 1;
    int row0 = seg0 * 16 + (lane >> 2), row1 = seg1 * 16 + (lane >> 2);
    int cu0 = (lane & 3) ^ ((row0 + (row0 >> 2)) & 3);
    int cu1 = (lane & 3) ^ ((row1 + (row1 >> 2)) & 3);
    const short* srcA0 = A + (size_t)(m0 + row0) * lda + cu0 * 8;
    const short* srcA1 = A + (size_t)(m0 + row1) * lda + cu1 * 8;
    const short* srcB0 = Bw + (size_t)(n0 + row0) * ldb + cu0 * 8;
    const short* srcB1 = Bw + (size_t)(n0 + row1) * ldb + cu1 * 8;
    short* dA0 = As + seg0 * 512; short* dA1 = As + seg1 * 512;
    short* dB0 = Bs + seg0 * 512; short* dB1 = Bs + seg1 * 512;
    const f32x4 vz = {0.f, 0.f, 0.f, 0.f};
    f32x4 acc[4][4];
    #pragma unroll
    for (int i = 0; i < 4; ++i)
        #pragma unroll
        for (int j = 0; j < 4; ++j) acc[i][j] = vz;
    for (int k0 = 0; k0 < K; k0 += 32) {
        if (k0) __syncthreads();
        gload_lds16(srcA0 + k0, dA0);
        gload_lds16(srcA1 + k0, dA1);
        gload_lds16(srcB0 + k0, dB0);
        gload_lds16(srcB1 + k0, dB1);
        __syncthreads();
        short8 af[4], bfr[4];
        #pragma unroll
        for (int i = 0; i < 4; ++i) {
            int ra = wm + i * 16 + lr;
            int rb = wn + i * 16 + lr;
            af[i]  = *(const short8*)(As + ra * 32 + ((lg ^ ((ra + (ra >> 2)) & 3)) * 8));
            bfr[i] = *(const short8*)(Bs + rb * 32 + ((lg ^ ((rb + (rb >> 2)) & 3)) * 8));
        }
        #pragma unroll
        for (int i = 0; i < 4; ++i)
            #pragma unroll
            for (int j = 0; j < 4; ++j)
                acc[i][j] = __builtin_amdgcn_mfma_f32_16x16x32_bf16(af[i], bfr[j], acc[i][j], 0, 0, 0);
    }
    int rb = m0 + wm + (lane >> 4) * 4;
    int cb = n0 + wn + lr;
    #pragma unroll
    for (int i = 0; i < 4; ++i)
        #pragma unroll
        for (int j = 0; j < 4; ++j)
            #pragma unroll
            for (int r = 0; r < 4; ++r) {
                int row = rb + i * 16 + r;
                int col = cb + j * 16;
                float v = acc[i][j][r];
                if (MODE == 0) ((short*)Cp)[(size_t)row * ldc + col] = f2bf(v);
                else if (MODE == 1) ((float*)Cp)[(size_t)row * ldc + col] += v;
                else if (col < NVOCAB) ((float*)Cp)[(size_t)row * NVOCAB + col] = v;
            }
}

// ---------- proj GEMM (BK=64) + inline split-K combine + residual + LN ----------
__global__ __launch_bounds__(256) void k_gemmproj(const short* __restrict__ cat,
        const short* __restrict__ Po, const float* __restrict__ Pml,
        const short* __restrict__ Bw, float* __restrict__ x,
        short* __restrict__ xn, const float* __restrict__ g,
        const float* __restrict__ b) {
    __shared__ __align__(16) short Afull[32 * 776];
    __shared__ __align__(16) short Bs[384 * 64];
    __shared__ float redS[4][32];
    __shared__ float redQ[4][32];
    int m0 = blockIdx.x * 32;
    int t = threadIdx.x;
    int wid = t >> 6, lane = t & 63;
    int lr = lane & 15, lg = lane >> 4;
    // ---- A loc half: row t>>3, feats (t&7)*48 (6 x short8) ----
    int arow = t >> 3, ac0 = (t & 7) * 48;
    {
        const short8* src = (const short8*)(cat + (size_t)(m0 + arow) * EM + ac0);
        short* dst = Afull + arow * 776 + ac0;
        #pragma unroll
        for (int i = 0; i < 6; ++i) *(short8*)(dst + i * 8) = src[i];
    }
    // ---- A att half: combine Po chunks (weights all 1 under fixed shift) ----
    {
        int qt = (((m0 >> 4) & 127)) + (arow >> 4);   // within-batch q-tile
        int bA = m0 >> 11;
        int gg = qt >> 4;
        int nch = gg + 1;
        int rowin = arow & 15;
        int ubase = 8 * gg * (gg + 1) + (qt & 15) * (gg + 1);
        float accv[48];
        #pragma unroll
        for (int e = 0; e < 48; ++e) accv[e] = 0.f;
        float L = 0.f;
        #pragma unroll
        for (int c = 0; c < 8; ++c) {
            if (c < nch) {
                int uu = ((ubase + c) << 2) | bA;
                L += Pml[uu * 32 + 16 + rowin];
                const short8* pp = (const short8*)(Po + ((size_t)uu * 16 + rowin) * 384 + ac0);
                #pragma unroll
                for (int v = 0; v < 6; ++v) {
                    short8 tv = pp[v];
                    #pragma unroll
                    for (int k = 0; k < 8; ++k) accv[v * 8 + k] += bf2f(tv[k]);
                }
            }
        }
        float invL = 1.f / L;
        short* dst = Afull + arow * 776 + DM + ac0;
        #pragma unroll
        for (int v = 0; v < 6; ++v) {
            short8 o8;
            #pragma unroll
            for (int k = 0; k < 8; ++k) o8[k] = f2bf(accv[v * 8 + k] * invL);
            *(short8*)(dst + v * 8) = o8;
        }
    }
    // ---- B staging (BK=64): 48 wave-uniform segs of 8 rows x 128B ----
    int brow0 = lane >> 3;                // row within seg
    int bck = (lane & 7) ^ (lane >> 3);   // swizzled source chunk
    const short* srcB[12]; short* dstB[12];
    #pragma unroll
    for (int i = 0; i < 12; ++i) {
        int seg = wid * 12 + i;
        int row = seg * 8 + brow0;
        srcB[i] = Bw + (size_t)row * EM + bck * 8;
        dstB[i] = Bs + seg * 512;
    }
    const f32x4 vz = {0.f, 0.f, 0.f, 0.f};
    f32x4 acc[2][6];
    #pragma unroll
    for (int i = 0; i < 2; ++i)
        #pragma unroll
        for (int j = 0; j < 6; ++j) acc[i][j] = vz;
    for (int k0 = 0; k0 < EM; k0 += 64) {
        __syncthreads();
        #pragma unroll
        for (int i = 0; i < 12; ++i)
            gload_lds16(srcB[i] + k0, dstB[i]);
        __syncthreads();
        #pragma unroll
        for (int ks = 0; ks < 2; ++ks) {
            short8 af[2], bfr[6];
            #pragma unroll
            for (int i = 0; i < 2; ++i)
                af[i] = *(const short8*)(Afull + (i * 16 + lr) * 776 + k0 + ks * 32 + lg * 8);
            #pragma unroll
            for (int j = 0; j < 6; ++j) {
                int rb = wid * 96 + j * 16 + lr;
                bfr[j] = *(const short8*)(Bs + rb * 64 + (((lg + ks * 4) ^ (rb & 7)) * 8));
            }
            #pragma unroll
            for (int i = 0; i < 2; ++i)
                #pragma unroll
                for (int j = 0; j < 6; ++j)
                    acc[i][j] = __builtin_amdgcn_mfma_f32_16x16x32_bf16(af[i], bfr[j], acc[i][j], 0, 0, 0);
        }
    }
    // epilogue: residual add + per-row stats
    #pragma unroll
    for (int i = 0; i < 2; ++i) {
        float rs[4], rq[4];
        #pragma unroll
        for (int r = 0; r < 4; ++r) {
            int row = m0 + i * 16 + lg * 4 + r;
            float s = 0.f, q2 = 0.f;
            #pragma unroll
            for (int j = 0; j < 6; ++j) {
                int col = wid * 96 + j * 16 + lr;
                float yv = x[(size_t)row * DM + col] + acc[i][j][r];
                acc[i][j][r] = yv;
                s += yv; q2 += yv * yv;
            }
            #pragma unroll
            for (int m = 1; m < 16; m <<= 1) { s += __shfl_xor(s, m); q2 += __shfl_xor(q2, m); }
            rs[r] = s; rq[r] = q2;
        }
        if (lr == 0) {
            #pragma unroll
            for (int r = 0; r < 4; ++r) {
                redS[wid][i * 16 + lg * 4 + r] = rs[r];
                redQ[wid][i * 16 + lg * 4 + r] = rq[r];
            }
        }
    }
    __syncthreads();
    #pragma unroll
    for (int i = 0; i < 2; ++i)
        #pragma unroll
        for (int r = 0; r < 4; ++r) {
            int lrow = i * 16 + lg * 4 + r;
            float s = redS[0][lrow] + redS[1][lrow] + redS[2][lrow] + redS[3][lrow];
            float q2 = redQ[0][lrow] + redQ[1][lrow] + redQ[2][lrow] + redQ[3][lrow];
            float mean = s * (1.f / DM);
            float var = q2 * (1.f / DM) - mean * mean;
            float rstd = rsqrtf(var + 1e-5f);
            int row = m0 + lrow;
            #pragma unroll
            for (int j = 0; j < 6; ++j) {
                int col = wid * 96 + j * 16 + lr;
                float yv = acc[i][j][r];
                x[(size_t)row * DM + col] = yv;
                xn[(size_t)row * DM + col] = f2bf((yv - mean) * rstd * g[col] + b[col]);
            }
        }
}

// ---------- split-K flash v9 (4 waves, K+V shared via LDS) ----------
__global__ __launch_bounds__(256) void k_flash(const short* __restrict__ qhb,
        const short* __restrict__ khb, const short* __restrict__ vT,
        short* __restrict__ Po, float* __restrict__ Pml) {
    int idx = blockIdx.x;            // 1024 blocks
    int xcd = idx & 7;
    int b = xcd >> 1;
    int unit = ((idx >> 3) << 1) | (xcd & 1);
    int gq = unit & 31, c = unit >> 5;
    if (c > (gq >> 2)) return;
    __shared__ __align__(16) short Vlds[384 * 40];
    __shared__ __align__(16) short Klds[32 * 64];
    __shared__ __align__(16) short Plds[4 * 16 * 40];
    int t = threadIdx.x;
    int wid = t >> 6, lane = t & 63;
    int lr = lane & 15, lg = lane >> 4;
    int qt = gq * 4 + wid;
    int g = qt >> 4;
    int tb = b * SEQ;
    int q0 = qt * 16;
    int nkbm = 2 * gq + 2;
    int kb0 = c * CH;
    int kb1 = min(kb0 + CH, nkbm);
    short* P = Plds + wid * (16 * 40);
    const float scale = 0.14433756729740643f; // 1/sqrt(48)
    const float CFIX = 8.f;
    const f32x4 vzero = {0.f, 0.f, 0.f, 0.f};

    short8 qf[2];
    #pragma unroll
    for (int ks = 0; ks < 2; ++ks)
        qf[ks] = *(const short8*)(qhb + (size_t)(tb + q0 + lr) * 64 + ks * 32 + lg * 8);

    f32x4 o[24];
    #pragma unroll
    for (int j = 0; j < 24; ++j) o[j] = vzero;
    float li[4];
    #pragma unroll
    for (int r = 0; r < 4; ++r) li[r] = 0.f;

    int vrow = t >> 2, vc = (t & 3) * 8;
    const short* vsrc0 = vT + (size_t)vrow * TOK + tb + vc;
    int krow = t >> 3, kc8 = (t & 7) * 8;
    const short* ksrc0 = khb + (size_t)(tb + krow) * 64 + kc8;

    short8 rv[6], rk;
    #pragma unroll
    for (int i = 0; i < 6; ++i)
        rv[i] = *(const short8*)(vsrc0 + (size_t)(i * 64) * TOK + kb0 * 32);
    rk = *(const short8*)(ksrc0 + (size_t)kb0 * 2048);

    for (int kb = kb0; kb < kb1; ++kb) {
        int kbase = kb * 32;
        __syncthreads();
        #pragma unroll
        for (int i = 0; i < 6; ++i)
            *(short8*)(Vlds + (vrow + i * 64) * 40 + vc) = rv[i];
        *(short8*)(Klds + krow * 64 + kc8) = rk;
        if (kb + 1 < kb1) {
            #pragma unroll
            for (int i = 0; i < 6; ++i)
                rv[i] = *(const short8*)(vsrc0 + (size_t)(i * 64) * TOK + kbase + 32);
            rk = *(const short8*)(ksrc0 + (size_t)(kb + 1) * 2048);
        }
        __syncthreads();
        short8 kf0a = *(const short8*)(Klds + lr * 64 + lg * 8);
        short8 kf0b = *(const short8*)(Klds + lr * 64 + 32 + lg * 8);
        short8 kf1a = *(const short8*)(Klds + (16 + lr) * 64 + lg * 8);
        short8 kf1b = *(const short8*)(Klds + (16 + lr) * 64 + 32 + lg * 8);

        f32x4 s0 = vzero, s1 = vzero;
        s0 = __builtin_amdgcn_mfma_f32_16x16x32_bf16(qf[0], kf0a, s0, 0, 0, 0);
        s0 = __builtin_amdgcn_mfma_f32_16x16x32_bf16(qf[1], kf0b, s0, 0, 0, 0);
        s1 = __builtin_amdgcn_mfma_f32_16x16x32_bf16(qf[0], kf1a, s1, 0, 0, 0);
        s1 = __builtin_amdgcn_mfma_f32_16x16x32_bf16(qf[1], kf1b, s1, 0, 0, 0);

        bool needmask = (kbase + 31 > q0);
        #pragma unroll
        for (int r = 0; r < 4; ++r) {
            float v0 = s0[r] * scale, v1 = s1[r] * scale;
            if (needmask) {
                int qg = q0 + lg * 4 + r;
                if (kbase + lr > qg) v0 = -1e30f;
                if (kbase + 16 + lr > qg) v1 = -1e30f;
            }
            float p0 = __expf(v0 - CFIX);
            float p1 = __expf(v1 - CFIX);
            li[r] += p0 + p1;
            s0[r] = p0; s1[r] = p1;
        }
        #pragma unroll
        for (int r = 0; r < 4; ++r) {
            P[(lg * 4 + r) * 40 + lr] = f2bf(s0[r]);
            P[(lg * 4 + r) * 40 + 16 + lr] = f2bf(s1[r]);
        }
        short8 pf = *(const short8*)(P + lr * 40 + lg * 8);
        #pragma unroll
        for (int j = 0; j < 24; ++j) {
            short8 vf = *(const short8*)(Vlds + (j * 16 + lr) * 40 + lg * 8);
            o[j] = __builtin_amdgcn_mfma_f32_16x16x32_bf16(pf, vf, o[j], 0, 0, 0);
        }
    }
    #pragma unroll
    for (int r = 0; r < 4; ++r) {
        float sum = li[r];
        #pragma unroll
        for (int d2 = 1; d2 < 16; d2 <<= 1) sum += __shfl_xor(sum, d2);
        li[r] = sum;
    }
    int uid = 8 * g * (g + 1) + (qt & 15) * (g + 1) + c;
    int sidx = (uid << 2) | b;
    size_t ob = (size_t)sidx * (16 * 384);
    #pragma unroll
    for (int j = 0; j < 24; ++j)
        #pragma unroll
        for (int r = 0; r < 4; ++r)
            Po[ob + (size_t)(lg * 4 + r) * 384 + j * 16 + lr] = f2bf(o[j][r]);
    if (lr == 0) {
        #pragma unroll
        for (int r = 0; r < 4; ++r)
            Pml[sidx * 32 + 16 + lg * 4 + r] = li[r];
    }
}

extern "C" void kernel_launch(void* const* d_in, const int* in_sizes, int n_in,
                              void* d_out, int out_size, void* d_ws, size_t ws_size,
                              hipStream_t stream) {
    const int*   q     = (const int*)d_in[0];
    const float* freqs = (const float*)d_in[1];
    const float* expw  = (const float*)d_in[2];
    const float* projw = (const float*)d_in[3];
    const float* blkg  = (const float*)d_in[4];
    const float* blkb  = (const float*)d_in[5];
    const float* lng   = (const float*)d_in[6];
    const float* lnb   = (const float*)d_in[7];
    const float* outw  = (const float*)d_in[8];
    float* out = (float*)d_out;

    char* p = (char*)d_ws;
    auto alloc = [&](size_t bytes) {
        char* r = p; p += (bytes + 255) & ~(size_t)255; return r;
    };
    float* x   = (float*)alloc((size_t)TOK * DM * 4);
    short* xn  = (short*)alloc((size_t)TOK * DM * 2);
    short* cat = (short*)alloc((size_t)TOK * EM * 2);
    short* vT  = (short*)alloc((size_t)DM * TOK * 2);
    short* qhb = (short*)alloc((size_t)TOK * 64 * 2);
    short* khb = (short*)alloc((size_t)TOK * 64 * 2);
    short* ewb = (short*)alloc((size_t)NBLK * HN * DM * 2);
    short* pwb = (short*)alloc((size_t)NBLK * DM * EM * 2);
    short* owb = (short*)alloc((size_t)128 * DM * 2);
    short* Po  = (short*)alloc((size_t)NUNITS * 16 * 384 * 2); // 28.3 MB
    float* Pml = (float*)alloc((size_t)NUNITS * 32 * 4);       // 294 KB

    k_setup<<<2048, 256, 0, stream>>>(expw, projw, outw, ewb, pwb, owb,
                                      q, freqs, lng, lnb, blkg, blkb, x, xn);

    for (int L = 0; L < NBLK; ++L) {
        k_gemmh<<<dim3(64, 7), 256, 0, stream>>>(xn, ewb + (size_t)L * HN * DM,
                                                 cat, vT, qhb, khb);
        k_flash<<<1024, 256, 0, stream>>>(qhb, khb, vT, Po, Pml);
        const float* gn = (L < NBLK - 1) ? blkg + (L + 1) * DM : lng;
        const float* bn = (L < NBLK - 1) ? blkb + (L + 1) * DM : lnb;
        k_gemmproj<<<256, 256, 0, stream>>>(cat, Po, Pml, pwb + (size_t)L * DM * EM,
                                            x, xn, gn, bn);
    }
    k_gemm<2><<<dim3(64, 1), 256, 0, stream>>>(xn, owb, DM, DM, DM, out, NVOCAB);
}